// Round 4
// baseline (4252.822 us; speedup 1.0000x reference)
//
#include <hip/hip_runtime.h>
#include <math.h>

// -------------------------------------------------------------------------
// VQ-VAE forward, fp32, round 4:
//  - VQ: 1024 single-wave blocks, 4-way-ILP fp64 distance, per-wave staging
//  - fused residual block (conv3x3+relu+conv1x1+add) with ping-pong buffers
//  - convt up0 COT 16
// Accumulation orders kept identical to the passing R3 kernel.
// Workspace: A(64MB) B(32MB) C(32MB) = 134.2 MB.
// -------------------------------------------------------------------------

#define DEV __device__ __forceinline__

DEV int rfl(int v) { return __builtin_amdgcn_readfirstlane(v); }

// ---------------- conv 4x4 stride2 pad1, one output row per wave ----------
template<int CIN, int COT, bool RELU_OUT, int OW>
__global__ __launch_bounds__(256) void conv4s2_row(
    const float* __restrict__ x, const float* __restrict__ w,
    const float* __restrict__ bias, float* __restrict__ y,
    int Hout, int Cout) {
  const int Win = OW * 2, Hin = Hout * 2;
  const int t = blockIdx.x * 256 + threadIdx.x;
  const int wo = t & (OW - 1);
  const int ho = rfl(t / OW);
  const int co0 = blockIdx.y * COT, n = blockIdx.z;

  float acc[COT];
#pragma unroll
  for (int u = 0; u < COT; u++) acc[u] = bias[co0 + u];

  const int iw0 = 2 * wo - 1;
  const int cA = iw0 < 0 ? 0 : iw0;
  const bool mA = iw0 >= 0;
  const int cD = (iw0 + 3 < Win) ? iw0 + 3 : Win - 1;
  const bool mD = iw0 + 3 < Win;

  for (int ci = 0; ci < CIN; ci++) {
    const float* xp = x + ((size_t)(n * CIN + ci)) * Hin * Win;
    const float* wp = w + ((size_t)(co0 * CIN + ci)) * 16;
#pragma unroll
    for (int kh = 0; kh < 4; kh++) {
      const int ih = 2 * ho - 1 + kh;
      if (ih >= 0 && ih < Hin) {
        const float* row = xp + (size_t)ih * Win;
        float x0 = row[cA];      x0 = mA ? x0 : 0.f;
        float x1 = row[iw0 + 1];
        float x2 = row[iw0 + 2];
        float x3 = row[cD];      x3 = mD ? x3 : 0.f;
#pragma unroll
        for (int u = 0; u < COT; u++) {
          const float* wr = wp + u * CIN * 16 + kh * 4;
          acc[u] = fmaf(x0, wr[0], acc[u]);
          acc[u] = fmaf(x1, wr[1], acc[u]);
          acc[u] = fmaf(x2, wr[2], acc[u]);
          acc[u] = fmaf(x3, wr[3], acc[u]);
        }
      }
    }
  }
#pragma unroll
  for (int u = 0; u < COT; u++) {
    float v = acc[u];
    if (RELU_OUT) v = fmaxf(v, 0.f);
    y[(((size_t)(n * Cout + co0 + u)) * Hout + ho) * OW + wo] = v;
  }
}

// ---------------- conv 3x3 stride1 pad1 on 64x64, one row per wave --------
template<int CIN, int COT, bool RELU_IN, bool RELU_OUT>
__global__ __launch_bounds__(256) void conv3_64(
    const float* __restrict__ x, const float* __restrict__ w,
    const float* __restrict__ bias, float* __restrict__ y, int Cout) {
  const int lane = threadIdx.x & 63;
  const int ho = rfl(blockIdx.x * 4 + (threadIdx.x >> 6));
  const int co0 = blockIdx.y * COT, n = blockIdx.z;

  float acc[COT];
#pragma unroll
  for (int u = 0; u < COT; u++) acc[u] = bias[co0 + u];

  const int cm = lane > 0 ? lane - 1 : 0;
  const bool mm = lane > 0;
  const int cp = lane < 63 ? lane + 1 : 63;
  const bool mp = lane < 63;

  for (int ci = 0; ci < CIN; ci++) {
    const float* xp = x + ((size_t)(n * CIN + ci)) * 4096;
    const float* wp = w + ((size_t)(co0 * CIN + ci)) * 9;
#pragma unroll
    for (int kh = 0; kh < 3; kh++) {
      const int ih = ho - 1 + kh;
      if (ih >= 0 && ih < 64) {
        const float* row = xp + (ih << 6);
        float xa = row[cm];   xa = mm ? xa : 0.f;
        float x0 = row[lane];
        float xb = row[cp];   xb = mp ? xb : 0.f;
        if (RELU_IN) {
          xa = fmaxf(xa, 0.f); x0 = fmaxf(x0, 0.f); xb = fmaxf(xb, 0.f);
        }
#pragma unroll
        for (int u = 0; u < COT; u++) {
          const float* wr = wp + u * CIN * 9 + kh * 3;
          acc[u] = fmaf(xa, wr[0], acc[u]);
          acc[u] = fmaf(x0, wr[1], acc[u]);
          acc[u] = fmaf(xb, wr[2], acc[u]);
        }
      }
    }
  }
#pragma unroll
  for (int u = 0; u < COT; u++) {
    float v = acc[u];
    if (RELU_OUT) v = fmaxf(v, 0.f);
    y[(((size_t)(n * Cout + co0 + u)) * 64 + ho) * 64 + lane] = v;
  }
}

// ---------------- fused residual block on 64x64 ---------------------------
// hout = hin + conv1x1(relu(conv3x3(relu(hin)))), CIN=128, CMID=32.
// One wave per (n, row); thread owns one position with all 32 mid channels.
// Ping-pong buffers (hin != hout) so the 3x3 halo never races the update.
__global__ __launch_bounds__(64) void res_block(
    const float* __restrict__ hin, const float* __restrict__ w1,
    const float* __restrict__ b1, const float* __restrict__ w2,
    const float* __restrict__ b2, float* __restrict__ hout) {
  const int lane = threadIdx.x;       // 0..63 = output column
  const int ho = blockIdx.x;          // 0..63
  const int n = blockIdx.y;

  float t[32];
#pragma unroll
  for (int u = 0; u < 32; u++) t[u] = b1[u];

  const int cm = lane > 0 ? lane - 1 : 0;
  const bool mm = lane > 0;
  const int cp = lane < 63 ? lane + 1 : 63;
  const bool mp = lane < 63;

  const float* xn = hin + ((size_t)n) * 128 * 4096;
  for (int ci = 0; ci < 128; ci++) {
    const float* xp = xn + ci * 4096;
    const float* wp = w1 + ci * 9;
#pragma unroll
    for (int kh = 0; kh < 3; kh++) {
      const int ih = ho - 1 + kh;
      if (ih >= 0 && ih < 64) {
        const float* row = xp + (ih << 6);
        float xa = row[cm];   xa = mm ? fmaxf(xa, 0.f) : 0.f;
        float x0 = fmaxf(row[lane], 0.f);
        float xb = row[cp];   xb = mp ? fmaxf(xb, 0.f) : 0.f;
#pragma unroll
        for (int u = 0; u < 32; u++) {
          const float* wr = wp + u * 128 * 9 + kh * 3;  // uniform -> s_load
          t[u] = fmaf(xa, wr[0], t[u]);
          t[u] = fmaf(x0, wr[1], t[u]);
          t[u] = fmaf(xb, wr[2], t[u]);
        }
      }
    }
  }
#pragma unroll
  for (int u = 0; u < 32; u++) t[u] = fmaxf(t[u], 0.f);

  const float* hp = hin + ((size_t)n) * 128 * 4096 + (ho << 6) + lane;
  float* op = hout + ((size_t)n) * 128 * 4096 + (ho << 6) + lane;
  for (int c = 0; c < 128; c++) {
    float acc = b2[c];
    const float* w2r = w2 + c * 32;                     // uniform -> s_load
#pragma unroll
    for (int u = 0; u < 32; u++) acc = fmaf(t[u], w2r[u], acc);
    op[(size_t)c * 4096] = hp[(size_t)c * 4096] + acc;
  }
}

// ---------------- conv 1x1 ----------------
template<int CIN, int COT, bool RELU_IN, bool ACCUM>
__global__ __launch_bounds__(256) void conv1x1_kernel(
    const float* __restrict__ x, const float* __restrict__ w,
    const float* __restrict__ bias, float* __restrict__ y,
    int HW, int Cout) {
  const int t = blockIdx.x * 256 + threadIdx.x;
  const int cog = blockIdx.y, n = blockIdx.z;
  const int co0 = cog * COT;

  float acc[COT];
#pragma unroll
  for (int u = 0; u < COT; u++) acc[u] = bias[co0 + u];

  for (int ci = 0; ci < CIN; ci++) {
    float xv = x[((size_t)(n * CIN + ci)) * HW + t];
    if (RELU_IN) xv = fmaxf(xv, 0.f);
#pragma unroll
    for (int u = 0; u < COT; u++)
      acc[u] = fmaf(xv, w[(co0 + u) * CIN + ci], acc[u]);
  }
#pragma unroll
  for (int u = 0; u < COT; u++) {
    size_t idx = ((size_t)(n * Cout + co0 + u)) * HW + t;
    if (ACCUM) y[idx] = y[idx] + acc[u];
    else       y[idx] = acc[u];
  }
}

// ---------------- ConvTranspose 4x4 stride2 pad1, one out-row per wave ----
template<int CIN, int COT, bool RELU_IN, bool RELU_OUT, int WH>
__global__ __launch_bounds__(256) void convt_row(
    const float* __restrict__ x, const float* __restrict__ w,
    const float* __restrict__ bias, float* __restrict__ y,
    int Hin, int Cout) {
  const int Hout = Hin * 2;
  const int t = blockIdx.x * 256 + threadIdx.x;
  const int a = t & (WH - 1);
  const int oh = rfl(t / WH);
  const int co0 = blockIdx.y * COT, n = blockIdx.z;

  float acc0[COT], acc1[COT];
#pragma unroll
  for (int u = 0; u < COT; u++) { acc0[u] = bias[co0 + u]; acc1[u] = bias[co0 + u]; }

  const int cm = a > 0 ? a - 1 : 0;
  const bool mm = a > 0;
  const int cp = a < WH - 1 ? a + 1 : WH - 1;
  const bool mp = a < WH - 1;

  const int kh0 = (oh + 1) & 1;
#pragma unroll
  for (int dh = 0; dh < 2; dh++) {
    const int kh = kh0 + 2 * dh;
    const int ih = (oh + 1 - kh) >> 1;
    if (ih >= 0 && ih < Hin) {
      for (int ci = 0; ci < CIN; ci++) {
        const float* row = x + (((size_t)(n * CIN + ci)) * Hin + ih) * WH;
        float x0  = row[a];
        float xm1 = row[cm];  xm1 = mm ? xm1 : 0.f;
        float xp1 = row[cp];  xp1 = mp ? xp1 : 0.f;
        if (RELU_IN) {
          x0 = fmaxf(x0, 0.f); xm1 = fmaxf(xm1, 0.f); xp1 = fmaxf(xp1, 0.f);
        }
        const float* wp = w + ((size_t)(ci * Cout + co0)) * 16 + kh * 4;
#pragma unroll
        for (int u = 0; u < COT; u++) {
          const float* wr = wp + u * 16;
          acc0[u] = fmaf(x0,  wr[1], acc0[u]);
          acc0[u] = fmaf(xm1, wr[3], acc0[u]);
          acc1[u] = fmaf(xp1, wr[0], acc1[u]);
          acc1[u] = fmaf(x0,  wr[2], acc1[u]);
        }
      }
    }
  }
#pragma unroll
  for (int u = 0; u < COT; u++) {
    float v0 = acc0[u], v1 = acc1[u];
    if (RELU_OUT) { v0 = fmaxf(v0, 0.f); v1 = fmaxf(v1, 0.f); }
    float* row = y + (((size_t)(n * Cout + co0 + u)) * Hout + oh) * (2 * WH);
    ((float2*)row)[a] = make_float2(v0, v1);
  }
}

// ---------------- Vector quantizer (in-place, fp64, 4-way ILP) ------------
// One wave per (n,row): 64 positions. Codebook staged tile-by-tile in LDS.
__global__ __launch_bounds__(64) void vq_kernel(
    const float* __restrict__ cb, float* __restrict__ zq) {
  __shared__ float cbs[64 * 64];     // [d][kk]
  __shared__ double cbn[64];
  const int lane = threadIdx.x;
  const int n = blockIdx.x >> 6, row = blockIdx.x & 63;
  const int hw = (row << 6) | lane;
  float* zp = zq + ((size_t)n) * 64 * 4096 + hw;
  float zr[64];
#pragma unroll
  for (int d = 0; d < 64; d++) zr[d] = zp[(size_t)d * 4096];

  int best = 0;
  double bestd = 1e300;
  for (int kt = 0; kt < 8; kt++) {
    __syncthreads();
    // lane stages column kk=lane: bank (d*64+lane)%32 = lane%32 -> conflict-free
    for (int d = 0; d < 64; d++)
      cbs[d * 64 + lane] = cb[d * 512 + kt * 64 + lane];
    __syncthreads();
    {
      double s = 0.0;
      for (int d = 0; d < 64; d++) {
        double c = (double)cbs[d * 64 + lane];
        s = fma(c, c, s);
      }
      cbn[lane] = s;
    }
    __syncthreads();
    for (int kk = 0; kk < 64; kk++) {
      double d0 = 0.0, d1 = 0.0, d2 = 0.0, d3 = 0.0;
#pragma unroll
      for (int d = 0; d < 64; d += 4) {
        d0 = fma((double)zr[d],     (double)cbs[(d)     * 64 + kk], d0);
        d1 = fma((double)zr[d + 1], (double)cbs[(d + 1) * 64 + kk], d1);
        d2 = fma((double)zr[d + 2], (double)cbs[(d + 2) * 64 + kk], d2);
        d3 = fma((double)zr[d + 3], (double)cbs[(d + 3) * 64 + kk], d3);
      }
      double dist = cbn[kk] - 2.0 * ((d0 + d1) + (d2 + d3));
      int k = kt * 64 + kk;
      if (dist < bestd) { bestd = dist; best = k; }
    }
  }
#pragma unroll
  for (int d = 0; d < 64; d++)
    zp[(size_t)d * 4096] = cb[d * 512 + best];
}

// -------------------------------------------------------------------------
extern "C" void kernel_launch(void* const* d_in, const int* in_sizes, int n_in,
                              void* d_out, int out_size, void* d_ws, size_t ws_size,
                              hipStream_t stream) {
  const float* x          = (const float*)d_in[0];
  const float* enc_w0     = (const float*)d_in[1];
  const float* enc_b0     = (const float*)d_in[2];
  const float* enc_w1     = (const float*)d_in[3];
  const float* enc_b1     = (const float*)d_in[4];
  const float* enc_wf     = (const float*)d_in[5];
  const float* enc_bf     = (const float*)d_in[6];
  const float* enc_res_w1 = (const float*)d_in[7];
  const float* enc_res_b1 = (const float*)d_in[8];
  const float* enc_res_w2 = (const float*)d_in[9];
  const float* enc_res_b2 = (const float*)d_in[10];
  const float* pre_w      = (const float*)d_in[11];
  const float* pre_b      = (const float*)d_in[12];
  const float* codebook   = (const float*)d_in[13];
  const float* dec_w      = (const float*)d_in[14];
  const float* dec_b      = (const float*)d_in[15];
  const float* dec_res_w1 = (const float*)d_in[16];
  const float* dec_res_b1 = (const float*)d_in[17];
  const float* dec_res_w2 = (const float*)d_in[18];
  const float* dec_res_b2 = (const float*)d_in[19];
  const float* up_w0      = (const float*)d_in[20];
  const float* up_b0      = (const float*)d_in[21];
  const float* up_w1      = (const float*)d_in[22];
  const float* up_b1      = (const float*)d_in[23];
  float* out = (float*)d_out;

  float* A = (float*)d_ws;         // 16,777,216 floats (64 MB)
  float* B = A + 16777216;         //  8,388,608 floats (32 MB)
  float* C = B + 8388608;          //  8,388,608 floats (32 MB)

  const dim3 blk(256);
  const dim3 blk64(64);
  const int N = 16;

  // --- Encoder ---
  conv4s2_row<3, 8, true, 128><<<dim3(64, 8, N), blk, 0, stream>>>(
      x, enc_w0, enc_b0, A, 128, 64);
  conv4s2_row<64, 16, true, 64><<<dim3(16, 8, N), blk, 0, stream>>>(
      A, enc_w1, enc_b1, B, 64, 128);
  conv3_64<128, 16, false, false><<<dim3(16, 8, N), blk, 0, stream>>>(
      B, enc_wf, enc_bf, C, 128);
  // enc res stack, ping-pong C -> B -> C
  res_block<<<dim3(64, N), blk64, 0, stream>>>(
      C, enc_res_w1, enc_res_b1, enc_res_w2, enc_res_b2, B);
  res_block<<<dim3(64, N), blk64, 0, stream>>>(
      B, enc_res_w1 + (size_t)32 * 128 * 9, enc_res_b1 + 32,
      enc_res_w2 + (size_t)128 * 32, enc_res_b2 + 128, C);
  // pre: relu(C) -> z in A
  conv1x1_kernel<128, 16, true, false><<<dim3(16, 4, N), blk, 0, stream>>>(
      C, pre_w, pre_b, A, 4096, 64);

  // --- VQ (in-place on A) ---
  vq_kernel<<<dim3(1024), blk64, 0, stream>>>(codebook, A);

  // --- Decoder ---
  conv3_64<64, 16, false, false><<<dim3(16, 8, N), blk, 0, stream>>>(
      A, dec_w, dec_b, B, 128);
  // dec res stack, ping-pong B -> C -> B
  res_block<<<dim3(64, N), blk64, 0, stream>>>(
      B, dec_res_w1, dec_res_b1, dec_res_w2, dec_res_b2, C);
  res_block<<<dim3(64, N), blk64, 0, stream>>>(
      C, dec_res_w1 + (size_t)32 * 128 * 9, dec_res_b1 + 32,
      dec_res_w2 + (size_t)128 * 32, dec_res_b2 + 128, B);
  // up0: relu(B) -> A(16,64,128,128), ReLU
  convt_row<128, 16, true, true, 64><<<dim3(32, 4, N), blk, 0, stream>>>(
      B, up_w0, up_b0, A, 64, 64);
  // up1: A -> out(16,3,256,256)
  convt_row<64, 3, false, false, 128><<<dim3(128, 1, N), blk, 0, stream>>>(
      A, up_w1, up_b1, out, 128, 3);
}

// Round 5
// 4144.205 us; speedup vs baseline: 1.0262x; 1.0262x over previous
//
#include <hip/hip_runtime.h>
#include <math.h>

// -------------------------------------------------------------------------
// VQ-VAE forward, fp32, round 5:
//  - convs identical to R3 (known-good 3105 us config)
//  - VQ v2: 4 waves/block split the CODE dim -> 16 waves/CU
//  - res_block v2: 4 waves/block split mid/out channels via LDS -> 16 waves/CU
// Workspace: A(64MB) B(32MB) C(32MB) = 134.2 MB.
// -------------------------------------------------------------------------

#define DEV __device__ __forceinline__

DEV int rfl(int v) { return __builtin_amdgcn_readfirstlane(v); }

// ---------------- conv 4x4 stride2 pad1, one output row per wave ----------
template<int CIN, int COT, bool RELU_OUT, int OW>
__global__ __launch_bounds__(256) void conv4s2_row(
    const float* __restrict__ x, const float* __restrict__ w,
    const float* __restrict__ bias, float* __restrict__ y,
    int Hout, int Cout) {
  const int Win = OW * 2, Hin = Hout * 2;
  const int t = blockIdx.x * 256 + threadIdx.x;
  const int wo = t & (OW - 1);
  const int ho = rfl(t / OW);
  const int co0 = blockIdx.y * COT, n = blockIdx.z;

  float acc[COT];
#pragma unroll
  for (int u = 0; u < COT; u++) acc[u] = bias[co0 + u];

  const int iw0 = 2 * wo - 1;
  const int cA = iw0 < 0 ? 0 : iw0;
  const bool mA = iw0 >= 0;
  const int cD = (iw0 + 3 < Win) ? iw0 + 3 : Win - 1;
  const bool mD = iw0 + 3 < Win;

  for (int ci = 0; ci < CIN; ci++) {
    const float* xp = x + ((size_t)(n * CIN + ci)) * Hin * Win;
    const float* wp = w + ((size_t)(co0 * CIN + ci)) * 16;
#pragma unroll
    for (int kh = 0; kh < 4; kh++) {
      const int ih = 2 * ho - 1 + kh;
      if (ih >= 0 && ih < Hin) {
        const float* row = xp + (size_t)ih * Win;
        float x0 = row[cA];      x0 = mA ? x0 : 0.f;
        float x1 = row[iw0 + 1];
        float x2 = row[iw0 + 2];
        float x3 = row[cD];      x3 = mD ? x3 : 0.f;
#pragma unroll
        for (int u = 0; u < COT; u++) {
          const float* wr = wp + u * CIN * 16 + kh * 4;
          acc[u] = fmaf(x0, wr[0], acc[u]);
          acc[u] = fmaf(x1, wr[1], acc[u]);
          acc[u] = fmaf(x2, wr[2], acc[u]);
          acc[u] = fmaf(x3, wr[3], acc[u]);
        }
      }
    }
  }
#pragma unroll
  for (int u = 0; u < COT; u++) {
    float v = acc[u];
    if (RELU_OUT) v = fmaxf(v, 0.f);
    y[(((size_t)(n * Cout + co0 + u)) * Hout + ho) * OW + wo] = v;
  }
}

// ---------------- conv 3x3 stride1 pad1 on 64x64, one row per wave --------
template<int CIN, int COT, bool RELU_IN, bool RELU_OUT>
__global__ __launch_bounds__(256) void conv3_64(
    const float* __restrict__ x, const float* __restrict__ w,
    const float* __restrict__ bias, float* __restrict__ y, int Cout) {
  const int lane = threadIdx.x & 63;
  const int ho = rfl(blockIdx.x * 4 + (threadIdx.x >> 6));
  const int co0 = blockIdx.y * COT, n = blockIdx.z;

  float acc[COT];
#pragma unroll
  for (int u = 0; u < COT; u++) acc[u] = bias[co0 + u];

  const int cm = lane > 0 ? lane - 1 : 0;
  const bool mm = lane > 0;
  const int cp = lane < 63 ? lane + 1 : 63;
  const bool mp = lane < 63;

  for (int ci = 0; ci < CIN; ci++) {
    const float* xp = x + ((size_t)(n * CIN + ci)) * 4096;
    const float* wp = w + ((size_t)(co0 * CIN + ci)) * 9;
#pragma unroll
    for (int kh = 0; kh < 3; kh++) {
      const int ih = ho - 1 + kh;
      if (ih >= 0 && ih < 64) {
        const float* row = xp + (ih << 6);
        float xa = row[cm];   xa = mm ? xa : 0.f;
        float x0 = row[lane];
        float xb = row[cp];   xb = mp ? xb : 0.f;
        if (RELU_IN) {
          xa = fmaxf(xa, 0.f); x0 = fmaxf(x0, 0.f); xb = fmaxf(xb, 0.f);
        }
#pragma unroll
        for (int u = 0; u < COT; u++) {
          const float* wr = wp + u * CIN * 9 + kh * 3;
          acc[u] = fmaf(xa, wr[0], acc[u]);
          acc[u] = fmaf(x0, wr[1], acc[u]);
          acc[u] = fmaf(xb, wr[2], acc[u]);
        }
      }
    }
  }
#pragma unroll
  for (int u = 0; u < COT; u++) {
    float v = acc[u];
    if (RELU_OUT) v = fmaxf(v, 0.f);
    y[(((size_t)(n * Cout + co0 + u)) * 64 + ho) * 64 + lane] = v;
  }
}

// ---------------- conv 1x1 ----------------
template<int CIN, int COT, bool RELU_IN, bool ACCUM>
__global__ __launch_bounds__(256) void conv1x1_kernel(
    const float* __restrict__ x, const float* __restrict__ w,
    const float* __restrict__ bias, float* __restrict__ y,
    int HW, int Cout) {
  const int t = blockIdx.x * 256 + threadIdx.x;
  const int cog = blockIdx.y, n = blockIdx.z;
  const int co0 = cog * COT;

  float acc[COT];
#pragma unroll
  for (int u = 0; u < COT; u++) acc[u] = bias[co0 + u];

  for (int ci = 0; ci < CIN; ci++) {
    float xv = x[((size_t)(n * CIN + ci)) * HW + t];
    if (RELU_IN) xv = fmaxf(xv, 0.f);
#pragma unroll
    for (int u = 0; u < COT; u++)
      acc[u] = fmaf(xv, w[(co0 + u) * CIN + ci], acc[u]);
  }
#pragma unroll
  for (int u = 0; u < COT; u++) {
    size_t idx = ((size_t)(n * Cout + co0 + u)) * HW + t;
    if (ACCUM) y[idx] = y[idx] + acc[u];
    else       y[idx] = acc[u];
  }
}

// ---------------- fused residual block v2 (4 waves/block) -----------------
// hout = hin + conv1x1(relu(conv3x3(relu(hin)))), CIN=128, CMID=32.
// Block 256 = 64 positions x 4 groups. 3x3: group g computes mids g*8..+8.
// Exchange via LDS [mid][pos] (2-way-free banks). 1x1: group g computes out
// channels g*32..+32 for its position. Accumulation order == R3 kernels.
__global__ __launch_bounds__(256) void res_block2(
    const float* __restrict__ hin, const float* __restrict__ w1,
    const float* __restrict__ b1, const float* __restrict__ w2,
    const float* __restrict__ b2, float* __restrict__ hout) {
  __shared__ float mid[32 * 64];      // [mid][pos]
  const int lane = threadIdx.x & 63;  // position column
  const int g = threadIdx.x >> 6;     // wave id 0..3
  const int ho = blockIdx.x;          // 0..63 (uniform)
  const int n = blockIdx.y;
  const int m0 = g * 8;

  float t[8];
#pragma unroll
  for (int u = 0; u < 8; u++) t[u] = b1[m0 + u];

  const int cm = lane > 0 ? lane - 1 : 0;
  const bool mm = lane > 0;
  const int cp = lane < 63 ? lane + 1 : 63;
  const bool mp = lane < 63;

  const float* xn = hin + ((size_t)n) * 128 * 4096;
  for (int ci = 0; ci < 128; ci++) {
    const float* xp = xn + ci * 4096;
    const float* wp = w1 + ci * 9;
#pragma unroll
    for (int kh = 0; kh < 3; kh++) {
      const int ih = ho - 1 + kh;
      if (ih >= 0 && ih < 64) {             // uniform branch
        const float* row = xp + (ih << 6);
        float xa = row[cm];   xa = mm ? fmaxf(xa, 0.f) : 0.f;
        float x0 = fmaxf(row[lane], 0.f);
        float xb = row[cp];   xb = mp ? fmaxf(xb, 0.f) : 0.f;
#pragma unroll
        for (int u = 0; u < 8; u++) {
          const float* wr = wp + (m0 + u) * 128 * 9 + kh * 3;  // s_load
          t[u] = fmaf(xa, wr[0], t[u]);
          t[u] = fmaf(x0, wr[1], t[u]);
          t[u] = fmaf(xb, wr[2], t[u]);
        }
      }
    }
  }
#pragma unroll
  for (int u = 0; u < 8; u++)
    mid[(m0 + u) * 64 + lane] = fmaxf(t[u], 0.f);
  __syncthreads();

  float vm[32];
#pragma unroll
  for (int u = 0; u < 32; u++) vm[u] = mid[u * 64 + lane];

  const int c0 = g * 32;
  for (int c = 0; c < 32; c++) {
    const int cc = c0 + c;
    float acc = b2[cc];
    const float* w2r = w2 + cc * 32;        // s_load
#pragma unroll
    for (int u = 0; u < 32; u++) acc = fmaf(vm[u], w2r[u], acc);
    const size_t idx = ((size_t)(n * 128 + cc)) * 4096 + (ho << 6) + lane;
    hout[idx] = hin[idx] + acc;
  }
}

// ---------------- ConvTranspose 4x4 stride2 pad1, one out-row per wave ----
template<int CIN, int COT, bool RELU_IN, bool RELU_OUT, int WH>
__global__ __launch_bounds__(256) void convt_row(
    const float* __restrict__ x, const float* __restrict__ w,
    const float* __restrict__ bias, float* __restrict__ y,
    int Hin, int Cout) {
  const int Hout = Hin * 2;
  const int t = blockIdx.x * 256 + threadIdx.x;
  const int a = t & (WH - 1);
  const int oh = rfl(t / WH);
  const int co0 = blockIdx.y * COT, n = blockIdx.z;

  float acc0[COT], acc1[COT];
#pragma unroll
  for (int u = 0; u < COT; u++) { acc0[u] = bias[co0 + u]; acc1[u] = bias[co0 + u]; }

  const int cm = a > 0 ? a - 1 : 0;
  const bool mm = a > 0;
  const int cp = a < WH - 1 ? a + 1 : WH - 1;
  const bool mp = a < WH - 1;

  const int kh0 = (oh + 1) & 1;
#pragma unroll
  for (int dh = 0; dh < 2; dh++) {
    const int kh = kh0 + 2 * dh;
    const int ih = (oh + 1 - kh) >> 1;
    if (ih >= 0 && ih < Hin) {
      for (int ci = 0; ci < CIN; ci++) {
        const float* row = x + (((size_t)(n * CIN + ci)) * Hin + ih) * WH;
        float x0  = row[a];
        float xm1 = row[cm];  xm1 = mm ? xm1 : 0.f;
        float xp1 = row[cp];  xp1 = mp ? xp1 : 0.f;
        if (RELU_IN) {
          x0 = fmaxf(x0, 0.f); xm1 = fmaxf(xm1, 0.f); xp1 = fmaxf(xp1, 0.f);
        }
        const float* wp = w + ((size_t)(ci * Cout + co0)) * 16 + kh * 4;
#pragma unroll
        for (int u = 0; u < COT; u++) {
          const float* wr = wp + u * 16;
          acc0[u] = fmaf(x0,  wr[1], acc0[u]);
          acc0[u] = fmaf(xm1, wr[3], acc0[u]);
          acc1[u] = fmaf(xp1, wr[0], acc1[u]);
          acc1[u] = fmaf(x0,  wr[2], acc1[u]);
        }
      }
    }
  }
#pragma unroll
  for (int u = 0; u < COT; u++) {
    float v0 = acc0[u], v1 = acc1[u];
    if (RELU_OUT) { v0 = fmaxf(v0, 0.f); v1 = fmaxf(v1, 0.f); }
    float* row = y + (((size_t)(n * Cout + co0 + u)) * Hout + oh) * (2 * WH);
    ((float2*)row)[a] = make_float2(v0, v1);
  }
}

// ---------------- Vector quantizer v2 (in-place, fp64, code-split) --------
// Block 256 = 64 positions x 4 code-groups; each thread scans 128 codes.
// Cross-group reduction with exact (dist,idx) ordering == sequential
// first-min. Grid 1024 blocks -> 16 waves/CU.
__global__ __launch_bounds__(256) void vq_kernel2(
    const float* __restrict__ cb, float* __restrict__ zq) {
  __shared__ float cbs[64 * 64];     // staged tile [d][kk]
  __shared__ double cbn[512];        // all code norms
  __shared__ double redD[256];
  __shared__ int    redI[256];
  __shared__ int    bestIdx[64];
  const int tid = threadIdx.x;
  const int lane = tid & 63, g = tid >> 6;
  const int n = blockIdx.x >> 6, row = blockIdx.x & 63;
  const int hw = (row << 6) | lane;
  float* zp = zq + ((size_t)n) * 64 * 4096 + hw;
  float zr[64];
#pragma unroll
  for (int d = 0; d < 64; d++) zr[d] = zp[(size_t)d * 4096];

  // all 512 norms once (2 per thread)
  for (int k = tid; k < 512; k += 256) {
    double s = 0.0;
    for (int d = 0; d < 64; d++) {
      double c = (double)cb[d * 512 + k];
      s = fma(c, c, s);
    }
    cbn[k] = s;
  }

  int best = 0;
  double bestd = 1e300;
  for (int kt = 0; kt < 8; kt++) {
    __syncthreads();
    for (int i = tid; i < 4096; i += 256) {
      int d = i >> 6, kk = i & 63;
      cbs[i] = cb[d * 512 + kt * 64 + kk];
    }
    __syncthreads();
#pragma unroll 1
    for (int j = 0; j < 16; j++) {
      const int kk = g * 16 + j;         // wave-uniform -> cbs broadcast
      double d0 = 0.0, d1 = 0.0, d2 = 0.0, d3 = 0.0;
#pragma unroll
      for (int d = 0; d < 64; d += 4) {
        d0 = fma((double)zr[d],     (double)cbs[(d)     * 64 + kk], d0);
        d1 = fma((double)zr[d + 1], (double)cbs[(d + 1) * 64 + kk], d1);
        d2 = fma((double)zr[d + 2], (double)cbs[(d + 2) * 64 + kk], d2);
        d3 = fma((double)zr[d + 3], (double)cbs[(d + 3) * 64 + kk], d3);
      }
      const int k = kt * 64 + kk;
      double dist = cbn[k] - 2.0 * ((d0 + d1) + (d2 + d3));
      if (dist < bestd) { bestd = dist; best = k; }
    }
  }
  redD[tid] = bestd;
  redI[tid] = best;
  __syncthreads();
  if (g == 0) {
    double bd = redD[lane];
    int bi = redI[lane];
#pragma unroll
    for (int gg = 1; gg < 4; gg++) {
      double d2 = redD[gg * 64 + lane];
      int i2 = redI[gg * 64 + lane];
      if (d2 < bd || (d2 == bd && i2 < bi)) { bd = d2; bi = i2; }
    }
    bestIdx[lane] = bi;
  }
  __syncthreads();
  const int k = bestIdx[lane];
#pragma unroll
  for (int j = 0; j < 16; j++) {
    const int d = g * 16 + j;
    zp[(size_t)d * 4096] = cb[d * 512 + k];
  }
}

// -------------------------------------------------------------------------
extern "C" void kernel_launch(void* const* d_in, const int* in_sizes, int n_in,
                              void* d_out, int out_size, void* d_ws, size_t ws_size,
                              hipStream_t stream) {
  const float* x          = (const float*)d_in[0];
  const float* enc_w0     = (const float*)d_in[1];
  const float* enc_b0     = (const float*)d_in[2];
  const float* enc_w1     = (const float*)d_in[3];
  const float* enc_b1     = (const float*)d_in[4];
  const float* enc_wf     = (const float*)d_in[5];
  const float* enc_bf     = (const float*)d_in[6];
  const float* enc_res_w1 = (const float*)d_in[7];
  const float* enc_res_b1 = (const float*)d_in[8];
  const float* enc_res_w2 = (const float*)d_in[9];
  const float* enc_res_b2 = (const float*)d_in[10];
  const float* pre_w      = (const float*)d_in[11];
  const float* pre_b      = (const float*)d_in[12];
  const float* codebook   = (const float*)d_in[13];
  const float* dec_w      = (const float*)d_in[14];
  const float* dec_b      = (const float*)d_in[15];
  const float* dec_res_w1 = (const float*)d_in[16];
  const float* dec_res_b1 = (const float*)d_in[17];
  const float* dec_res_w2 = (const float*)d_in[18];
  const float* dec_res_b2 = (const float*)d_in[19];
  const float* up_w0      = (const float*)d_in[20];
  const float* up_b0      = (const float*)d_in[21];
  const float* up_w1      = (const float*)d_in[22];
  const float* up_b1      = (const float*)d_in[23];
  float* out = (float*)d_out;

  float* A = (float*)d_ws;         // 16,777,216 floats (64 MB)
  float* B = A + 16777216;         //  8,388,608 floats (32 MB)
  float* C = B + 8388608;          //  8,388,608 floats (32 MB)

  const dim3 blk(256);
  const int N = 16;

  // --- Encoder (identical to R3) ---
  conv4s2_row<3, 8, true, 128><<<dim3(64, 8, N), blk, 0, stream>>>(
      x, enc_w0, enc_b0, A, 128, 64);
  conv4s2_row<64, 16, true, 64><<<dim3(16, 8, N), blk, 0, stream>>>(
      A, enc_w1, enc_b1, B, 64, 128);
  conv3_64<128, 16, false, false><<<dim3(16, 8, N), blk, 0, stream>>>(
      B, enc_wf, enc_bf, C, 128);
  // enc res stack, ping-pong C -> B -> C
  res_block2<<<dim3(64, N), blk, 0, stream>>>(
      C, enc_res_w1, enc_res_b1, enc_res_w2, enc_res_b2, B);
  res_block2<<<dim3(64, N), blk, 0, stream>>>(
      B, enc_res_w1 + (size_t)32 * 128 * 9, enc_res_b1 + 32,
      enc_res_w2 + (size_t)128 * 32, enc_res_b2 + 128, C);
  // pre: relu(C) -> z in A
  conv1x1_kernel<128, 16, true, false><<<dim3(16, 4, N), blk, 0, stream>>>(
      C, pre_w, pre_b, A, 4096, 64);

  // --- VQ (in-place on A) ---
  vq_kernel2<<<dim3(1024), blk, 0, stream>>>(codebook, A);

  // --- Decoder ---
  conv3_64<64, 16, false, false><<<dim3(16, 8, N), blk, 0, stream>>>(
      A, dec_w, dec_b, B, 128);
  // dec res stack, ping-pong B -> C -> B
  res_block2<<<dim3(64, N), blk, 0, stream>>>(
      B, dec_res_w1, dec_res_b1, dec_res_w2, dec_res_b2, C);
  res_block2<<<dim3(64, N), blk, 0, stream>>>(
      C, dec_res_w1 + (size_t)32 * 128 * 9, dec_res_b1 + 32,
      dec_res_w2 + (size_t)128 * 32, dec_res_b2 + 128, B);
  // up0: relu(B) -> A(16,64,128,128), ReLU  (R3 config)
  convt_row<128, 8, true, true, 64><<<dim3(32, 8, N), blk, 0, stream>>>(
      B, up_w0, up_b0, A, 64, 64);
  // up1: A -> out(16,3,256,256)
  convt_row<64, 3, false, false, 128><<<dim3(128, 1, N), blk, 0, stream>>>(
      A, up_w1, up_b1, out, 128, 3);
}

// Round 6
// 3223.695 us; speedup vs baseline: 1.3192x; 1.2855x over previous
//
#include <hip/hip_runtime.h>
#include <math.h>

// -------------------------------------------------------------------------
// VQ-VAE forward, fp32, round 6:
//  - 3x3 / convT / conv1 kernels rewritten with wave-shuffle neighbor
//    exchange (64-wide row == wave) + 1-deep ci prefetch: 3x fewer x loads,
//    load latency hidden behind the FMA burst.
//  - conv0, up1, pre-1x1, VQ unchanged (known-good).
// Workspace: A(64MB) B(32MB) C(32MB) = 134.2 MB.
// -------------------------------------------------------------------------

#define DEV __device__ __forceinline__

DEV int rfl(int v) { return __builtin_amdgcn_readfirstlane(v); }

// ---------------- conv 4x4 stride2 pad1 (generic, used for conv0) ---------
template<int CIN, int COT, bool RELU_OUT, int OW>
__global__ __launch_bounds__(256) void conv4s2_row(
    const float* __restrict__ x, const float* __restrict__ w,
    const float* __restrict__ bias, float* __restrict__ y,
    int Hout, int Cout) {
  const int Win = OW * 2, Hin = Hout * 2;
  const int t = blockIdx.x * 256 + threadIdx.x;
  const int wo = t & (OW - 1);
  const int ho = rfl(t / OW);
  const int co0 = blockIdx.y * COT, n = blockIdx.z;

  float acc[COT];
#pragma unroll
  for (int u = 0; u < COT; u++) acc[u] = bias[co0 + u];

  const int iw0 = 2 * wo - 1;
  const int cA = iw0 < 0 ? 0 : iw0;
  const bool mA = iw0 >= 0;
  const int cD = (iw0 + 3 < Win) ? iw0 + 3 : Win - 1;
  const bool mD = iw0 + 3 < Win;

  for (int ci = 0; ci < CIN; ci++) {
    const float* xp = x + ((size_t)(n * CIN + ci)) * Hin * Win;
    const float* wp = w + ((size_t)(co0 * CIN + ci)) * 16;
#pragma unroll
    for (int kh = 0; kh < 4; kh++) {
      const int ih = 2 * ho - 1 + kh;
      if (ih >= 0 && ih < Hin) {
        const float* row = xp + (size_t)ih * Win;
        float x0 = row[cA];      x0 = mA ? x0 : 0.f;
        float x1 = row[iw0 + 1];
        float x2 = row[iw0 + 2];
        float x3 = row[cD];      x3 = mD ? x3 : 0.f;
#pragma unroll
        for (int u = 0; u < COT; u++) {
          const float* wr = wp + u * CIN * 16 + kh * 4;
          acc[u] = fmaf(x0, wr[0], acc[u]);
          acc[u] = fmaf(x1, wr[1], acc[u]);
          acc[u] = fmaf(x2, wr[2], acc[u]);
          acc[u] = fmaf(x3, wr[3], acc[u]);
        }
      }
    }
  }
#pragma unroll
  for (int u = 0; u < COT; u++) {
    float v = acc[u];
    if (RELU_OUT) v = fmaxf(v, 0.f);
    y[(((size_t)(n * Cout + co0 + u)) * Hout + ho) * OW + wo] = v;
  }
}

// ---------------- conv 4x4 s2 p1, Hin=Win=128 -> 64x64, shuffle+prefetch ---
// Wave = one output row (64 wide). Thread loads float2 (cols 2wo,2wo+1);
// cols 2wo-1 / 2wo+2 come from neighbor lanes via shuffle.
template<int CIN, int COT, bool RELU_OUT>
__global__ __launch_bounds__(256) void conv4s2_64v3(
    const float* __restrict__ x, const float* __restrict__ w,
    const float* __restrict__ bias, float* __restrict__ y, int Cout) {
  const int lane = threadIdx.x & 63;            // == wo
  const int ho = rfl(blockIdx.x * 4 + (threadIdx.x >> 6));
  const int co0 = blockIdx.y * COT, n = blockIdx.z;

  float acc[COT];
#pragma unroll
  for (int u = 0; u < COT; u++) acc[u] = bias[co0 + u];

  int ro[4]; bool rv[4];
#pragma unroll
  for (int kh = 0; kh < 4; kh++) {
    const int ih = 2 * ho - 1 + kh;
    rv[kh] = (ih >= 0 && ih < 128);
    ro[kh] = (rv[kh] ? ih : 0) * 128;
  }
  const float* xb = x + ((size_t)(n * CIN)) * 16384;

  float2 p[4];
#pragma unroll
  for (int kh = 0; kh < 4; kh++)
    p[kh] = ((const float2*)(xb + ro[kh]))[lane];

  for (int ci = 0; ci < CIN; ci++) {
    float2 c[4];
#pragma unroll
    for (int kh = 0; kh < 4; kh++) {
      c[kh].x = rv[kh] ? p[kh].x : 0.f;
      c[kh].y = rv[kh] ? p[kh].y : 0.f;
    }
    const int cn = (ci < CIN - 1 ? ci + 1 : ci) * 16384;
#pragma unroll
    for (int kh = 0; kh < 4; kh++)
      p[kh] = ((const float2*)(xb + cn + ro[kh]))[lane];

    const float* wp = w + ((size_t)(co0 * CIN + ci)) * 16;
#pragma unroll
    for (int kh = 0; kh < 4; kh++) {
      const float e = c[kh].x, o = c[kh].y;      // cols 2wo, 2wo+1
      float xm = __shfl_up(o, 1);  xm = lane > 0  ? xm : 0.f;  // col 2wo-1
      float xp = __shfl_down(e, 1); xp = lane < 63 ? xp : 0.f; // col 2wo+2
#pragma unroll
      for (int u = 0; u < COT; u++) {
        const float* wr = wp + u * CIN * 16 + kh * 4;
        acc[u] = fmaf(xm, wr[0], acc[u]);
        acc[u] = fmaf(e,  wr[1], acc[u]);
        acc[u] = fmaf(o,  wr[2], acc[u]);
        acc[u] = fmaf(xp, wr[3], acc[u]);
      }
    }
  }
#pragma unroll
  for (int u = 0; u < COT; u++) {
    float v = acc[u];
    if (RELU_OUT) v = fmaxf(v, 0.f);
    y[(((size_t)(n * Cout + co0 + u)) * 64 + ho) * 64 + lane] = v;
  }
}

// ---------------- conv 3x3 s1 p1 on 64x64, shuffle + prefetch -------------
template<int CIN, int COT, bool RELU_IN, bool RELU_OUT>
__global__ __launch_bounds__(256) void conv3_64v3(
    const float* __restrict__ x, const float* __restrict__ w,
    const float* __restrict__ bias, float* __restrict__ y, int Cout) {
  const int lane = threadIdx.x & 63;
  const int ho = rfl(blockIdx.x * 4 + (threadIdx.x >> 6));
  const int co0 = blockIdx.y * COT, n = blockIdx.z;

  float acc[COT];
#pragma unroll
  for (int u = 0; u < COT; u++) acc[u] = bias[co0 + u];

  const bool v0 = ho > 0, v2 = ho < 63;
  const int o0 = v0 ? -64 : 0, o2 = v2 ? 64 : 0;
  const float* xb = x + ((size_t)(n * CIN)) * 4096 + (ho << 6) + lane;

  float p0 = xb[o0], p1 = xb[0], p2 = xb[o2];
  for (int ci = 0; ci < CIN; ci++) {
    float c0 = v0 ? p0 : 0.f, c1 = p1, c2 = v2 ? p2 : 0.f;
    if (RELU_IN) {
      c0 = fmaxf(c0, 0.f); c1 = fmaxf(c1, 0.f); c2 = fmaxf(c2, 0.f);
    }
    const int cn = (ci < CIN - 1 ? ci + 1 : ci) * 4096;
    p0 = xb[cn + o0]; p1 = xb[cn]; p2 = xb[cn + o2];

    const float* wp = w + ((size_t)(co0 * CIN + ci)) * 9;
#pragma unroll
    for (int kh = 0; kh < 3; kh++) {
      const float v = kh == 0 ? c0 : (kh == 1 ? c1 : c2);
      float xa = __shfl_up(v, 1);   xa = lane > 0  ? xa : 0.f;
      float xc = __shfl_down(v, 1); xc = lane < 63 ? xc : 0.f;
#pragma unroll
      for (int u = 0; u < COT; u++) {
        const float* wr = wp + u * CIN * 9 + kh * 3;
        acc[u] = fmaf(xa, wr[0], acc[u]);
        acc[u] = fmaf(v,  wr[1], acc[u]);
        acc[u] = fmaf(xc, wr[2], acc[u]);
      }
    }
  }
#pragma unroll
  for (int u = 0; u < COT; u++) {
    float v = acc[u];
    if (RELU_OUT) v = fmaxf(v, 0.f);
    y[(((size_t)(n * Cout + co0 + u)) * 64 + ho) * 64 + lane] = v;
  }
}

// ---------------- fused residual block v3 -----------------
// hout = hin + conv1x1(relu(conv3x3(relu(hin)))). Block 256 = row x 4 waves;
// wave g computes mids g*8..+8 (shuffle+prefetch), LDS exchange, then 1x1
// over out channels g*32..+32.
__global__ __launch_bounds__(256) void res_block3(
    const float* __restrict__ hin, const float* __restrict__ w1,
    const float* __restrict__ b1, const float* __restrict__ w2,
    const float* __restrict__ b2, float* __restrict__ hout) {
  __shared__ float mid[32 * 64];
  const int lane = threadIdx.x & 63;
  const int g = threadIdx.x >> 6;
  const int ho = blockIdx.x;
  const int n = blockIdx.y;
  const int m0 = g * 8;

  float t[8];
#pragma unroll
  for (int u = 0; u < 8; u++) t[u] = b1[m0 + u];

  const bool v0 = ho > 0, v2 = ho < 63;
  const int o0 = v0 ? -64 : 0, o2 = v2 ? 64 : 0;
  const float* xb = hin + ((size_t)n) * 128 * 4096 + (ho << 6) + lane;

  float p0 = xb[o0], p1 = xb[0], p2 = xb[o2];
  for (int ci = 0; ci < 128; ci++) {
    float c0 = v0 ? fmaxf(p0, 0.f) : 0.f;
    float c1 = fmaxf(p1, 0.f);
    float c2 = v2 ? fmaxf(p2, 0.f) : 0.f;
    const int cn = (ci < 127 ? ci + 1 : ci) * 4096;
    p0 = xb[cn + o0]; p1 = xb[cn]; p2 = xb[cn + o2];

    const float* wp = w1 + ci * 9;
#pragma unroll
    for (int kh = 0; kh < 3; kh++) {
      const float v = kh == 0 ? c0 : (kh == 1 ? c1 : c2);
      float xa = __shfl_up(v, 1);   xa = lane > 0  ? xa : 0.f;
      float xc = __shfl_down(v, 1); xc = lane < 63 ? xc : 0.f;
#pragma unroll
      for (int u = 0; u < 8; u++) {
        const float* wr = wp + (m0 + u) * 128 * 9 + kh * 3;
        t[u] = fmaf(xa, wr[0], t[u]);
        t[u] = fmaf(v,  wr[1], t[u]);
        t[u] = fmaf(xc, wr[2], t[u]);
      }
    }
  }
#pragma unroll
  for (int u = 0; u < 8; u++)
    mid[(m0 + u) * 64 + lane] = fmaxf(t[u], 0.f);
  __syncthreads();

  float vm[32];
#pragma unroll
  for (int u = 0; u < 32; u++) vm[u] = mid[u * 64 + lane];

  const int c0g = g * 32;
  for (int c = 0; c < 32; c++) {
    const int cc = c0g + c;
    float acc = b2[cc];
    const float* w2r = w2 + cc * 32;
#pragma unroll
    for (int u = 0; u < 32; u++) acc = fmaf(vm[u], w2r[u], acc);
    const size_t idx = ((size_t)(n * 128 + cc)) * 4096 + (ho << 6) + lane;
    hout[idx] = hin[idx] + acc;
  }
}

// ---------------- conv 1x1 ----------------
template<int CIN, int COT, bool RELU_IN, bool ACCUM>
__global__ __launch_bounds__(256) void conv1x1_kernel(
    const float* __restrict__ x, const float* __restrict__ w,
    const float* __restrict__ bias, float* __restrict__ y,
    int HW, int Cout) {
  const int t = blockIdx.x * 256 + threadIdx.x;
  const int cog = blockIdx.y, n = blockIdx.z;
  const int co0 = cog * COT;

  float acc[COT];
#pragma unroll
  for (int u = 0; u < COT; u++) acc[u] = bias[co0 + u];

  for (int ci = 0; ci < CIN; ci++) {
    float xv = x[((size_t)(n * CIN + ci)) * HW + t];
    if (RELU_IN) xv = fmaxf(xv, 0.f);
#pragma unroll
    for (int u = 0; u < COT; u++)
      acc[u] = fmaf(xv, w[(co0 + u) * CIN + ci], acc[u]);
  }
#pragma unroll
  for (int u = 0; u < COT; u++) {
    size_t idx = ((size_t)(n * Cout + co0 + u)) * HW + t;
    if (ACCUM) y[idx] = y[idx] + acc[u];
    else       y[idx] = acc[u];
  }
}

// ---------------- ConvTranspose 4x4 s2 p1, WH=64, shuffle+prefetch --------
template<int CIN, int COT, bool RELU_IN, bool RELU_OUT>
__global__ __launch_bounds__(256) void convt_64v3(
    const float* __restrict__ x, const float* __restrict__ w,
    const float* __restrict__ bias, float* __restrict__ y,
    int Hin, int Cout) {
  const int Hout = Hin * 2;
  const int a = threadIdx.x & 63;
  const int oh = rfl(blockIdx.x * 4 + (threadIdx.x >> 6));
  const int co0 = blockIdx.y * COT, n = blockIdx.z;

  float acc0[COT], acc1[COT];
#pragma unroll
  for (int u = 0; u < COT; u++) { acc0[u] = bias[co0 + u]; acc1[u] = bias[co0 + u]; }

  const int kh0 = (oh + 1) & 1;
#pragma unroll
  for (int dh = 0; dh < 2; dh++) {
    const int kh = kh0 + 2 * dh;
    const int ih = (oh + 1 - kh) >> 1;
    if (ih >= 0 && ih < Hin) {               // uniform
      const float* xb = x + (((size_t)(n * CIN)) * Hin + ih) * 64 + a;
      float p = xb[0];
      for (int ci = 0; ci < CIN; ci++) {
        float x0 = p;
        if (RELU_IN) x0 = fmaxf(x0, 0.f);
        p = xb[(ci < CIN - 1 ? ci + 1 : ci) * Hin * 64];
        float xm1 = __shfl_up(x0, 1);   xm1 = a > 0  ? xm1 : 0.f;
        float xp1 = __shfl_down(x0, 1); xp1 = a < 63 ? xp1 : 0.f;
        const float* wp = w + ((size_t)(ci * Cout + co0)) * 16 + kh * 4;
#pragma unroll
        for (int u = 0; u < COT; u++) {
          const float* wr = wp + u * 16;
          acc0[u] = fmaf(x0,  wr[1], acc0[u]);
          acc0[u] = fmaf(xm1, wr[3], acc0[u]);
          acc1[u] = fmaf(xp1, wr[0], acc1[u]);
          acc1[u] = fmaf(x0,  wr[2], acc1[u]);
        }
      }
    }
  }
#pragma unroll
  for (int u = 0; u < COT; u++) {
    float v0 = acc0[u], v1 = acc1[u];
    if (RELU_OUT) { v0 = fmaxf(v0, 0.f); v1 = fmaxf(v1, 0.f); }
    float* row = y + (((size_t)(n * Cout + co0 + u)) * Hout + oh) * 128;
    ((float2*)row)[a] = make_float2(v0, v1);
  }
}

// ---------------- ConvTranspose 4x4 s2 p1 (generic, used for up1) ---------
template<int CIN, int COT, bool RELU_IN, bool RELU_OUT, int WH>
__global__ __launch_bounds__(256) void convt_row(
    const float* __restrict__ x, const float* __restrict__ w,
    const float* __restrict__ bias, float* __restrict__ y,
    int Hin, int Cout) {
  const int Hout = Hin * 2;
  const int t = blockIdx.x * 256 + threadIdx.x;
  const int a = t & (WH - 1);
  const int oh = rfl(t / WH);
  const int co0 = blockIdx.y * COT, n = blockIdx.z;

  float acc0[COT], acc1[COT];
#pragma unroll
  for (int u = 0; u < COT; u++) { acc0[u] = bias[co0 + u]; acc1[u] = bias[co0 + u]; }

  const int cm = a > 0 ? a - 1 : 0;
  const bool mm = a > 0;
  const int cp = a < WH - 1 ? a + 1 : WH - 1;
  const bool mp = a < WH - 1;

  const int kh0 = (oh + 1) & 1;
#pragma unroll
  for (int dh = 0; dh < 2; dh++) {
    const int kh = kh0 + 2 * dh;
    const int ih = (oh + 1 - kh) >> 1;
    if (ih >= 0 && ih < Hin) {
      for (int ci = 0; ci < CIN; ci++) {
        const float* row = x + (((size_t)(n * CIN + ci)) * Hin + ih) * WH;
        float x0  = row[a];
        float xm1 = row[cm];  xm1 = mm ? xm1 : 0.f;
        float xp1 = row[cp];  xp1 = mp ? xp1 : 0.f;
        if (RELU_IN) {
          x0 = fmaxf(x0, 0.f); xm1 = fmaxf(xm1, 0.f); xp1 = fmaxf(xp1, 0.f);
        }
        const float* wp = w + ((size_t)(ci * Cout + co0)) * 16 + kh * 4;
#pragma unroll
        for (int u = 0; u < COT; u++) {
          const float* wr = wp + u * 16;
          acc0[u] = fmaf(x0,  wr[1], acc0[u]);
          acc0[u] = fmaf(xm1, wr[3], acc0[u]);
          acc1[u] = fmaf(xp1, wr[0], acc1[u]);
          acc1[u] = fmaf(x0,  wr[2], acc1[u]);
        }
      }
    }
  }
#pragma unroll
  for (int u = 0; u < COT; u++) {
    float v0 = acc0[u], v1 = acc1[u];
    if (RELU_OUT) { v0 = fmaxf(v0, 0.f); v1 = fmaxf(v1, 0.f); }
    float* row = y + (((size_t)(n * Cout + co0 + u)) * Hout + oh) * (2 * WH);
    ((float2*)row)[a] = make_float2(v0, v1);
  }
}

// ---------------- Vector quantizer v2 (in-place, fp64, code-split) --------
__global__ __launch_bounds__(256) void vq_kernel2(
    const float* __restrict__ cb, float* __restrict__ zq) {
  __shared__ float cbs[64 * 64];
  __shared__ double cbn[512];
  __shared__ double redD[256];
  __shared__ int    redI[256];
  __shared__ int    bestIdx[64];
  const int tid = threadIdx.x;
  const int lane = tid & 63, g = tid >> 6;
  const int n = blockIdx.x >> 6, row = blockIdx.x & 63;
  const int hw = (row << 6) | lane;
  float* zp = zq + ((size_t)n) * 64 * 4096 + hw;
  float zr[64];
#pragma unroll
  for (int d = 0; d < 64; d++) zr[d] = zp[(size_t)d * 4096];

  for (int k = tid; k < 512; k += 256) {
    double s = 0.0;
    for (int d = 0; d < 64; d++) {
      double c = (double)cb[d * 512 + k];
      s = fma(c, c, s);
    }
    cbn[k] = s;
  }

  int best = 0;
  double bestd = 1e300;
  for (int kt = 0; kt < 8; kt++) {
    __syncthreads();
    for (int i = tid; i < 4096; i += 256) {
      int d = i >> 6, kk = i & 63;
      cbs[i] = cb[d * 512 + kt * 64 + kk];
    }
    __syncthreads();
#pragma unroll 1
    for (int j = 0; j < 16; j++) {
      const int kk = g * 16 + j;
      double d0 = 0.0, d1 = 0.0, d2 = 0.0, d3 = 0.0;
#pragma unroll
      for (int d = 0; d < 64; d += 4) {
        d0 = fma((double)zr[d],     (double)cbs[(d)     * 64 + kk], d0);
        d1 = fma((double)zr[d + 1], (double)cbs[(d + 1) * 64 + kk], d1);
        d2 = fma((double)zr[d + 2], (double)cbs[(d + 2) * 64 + kk], d2);
        d3 = fma((double)zr[d + 3], (double)cbs[(d + 3) * 64 + kk], d3);
      }
      const int k = kt * 64 + kk;
      double dist = cbn[k] - 2.0 * ((d0 + d1) + (d2 + d3));
      if (dist < bestd) { bestd = dist; best = k; }
    }
  }
  redD[tid] = bestd;
  redI[tid] = best;
  __syncthreads();
  if (g == 0) {
    double bd = redD[lane];
    int bi = redI[lane];
#pragma unroll
    for (int gg = 1; gg < 4; gg++) {
      double d2 = redD[gg * 64 + lane];
      int i2 = redI[gg * 64 + lane];
      if (d2 < bd || (d2 == bd && i2 < bi)) { bd = d2; bi = i2; }
    }
    bestIdx[lane] = bi;
  }
  __syncthreads();
  const int k = bestIdx[lane];
#pragma unroll
  for (int j = 0; j < 16; j++) {
    const int d = g * 16 + j;
    zp[(size_t)d * 4096] = cb[d * 512 + k];
  }
}

// -------------------------------------------------------------------------
extern "C" void kernel_launch(void* const* d_in, const int* in_sizes, int n_in,
                              void* d_out, int out_size, void* d_ws, size_t ws_size,
                              hipStream_t stream) {
  const float* x          = (const float*)d_in[0];
  const float* enc_w0     = (const float*)d_in[1];
  const float* enc_b0     = (const float*)d_in[2];
  const float* enc_w1     = (const float*)d_in[3];
  const float* enc_b1     = (const float*)d_in[4];
  const float* enc_wf     = (const float*)d_in[5];
  const float* enc_bf     = (const float*)d_in[6];
  const float* enc_res_w1 = (const float*)d_in[7];
  const float* enc_res_b1 = (const float*)d_in[8];
  const float* enc_res_w2 = (const float*)d_in[9];
  const float* enc_res_b2 = (const float*)d_in[10];
  const float* pre_w      = (const float*)d_in[11];
  const float* pre_b      = (const float*)d_in[12];
  const float* codebook   = (const float*)d_in[13];
  const float* dec_w      = (const float*)d_in[14];
  const float* dec_b      = (const float*)d_in[15];
  const float* dec_res_w1 = (const float*)d_in[16];
  const float* dec_res_b1 = (const float*)d_in[17];
  const float* dec_res_w2 = (const float*)d_in[18];
  const float* dec_res_b2 = (const float*)d_in[19];
  const float* up_w0      = (const float*)d_in[20];
  const float* up_b0      = (const float*)d_in[21];
  const float* up_w1      = (const float*)d_in[22];
  const float* up_b1      = (const float*)d_in[23];
  float* out = (float*)d_out;

  float* A = (float*)d_ws;         // 16,777,216 floats (64 MB)
  float* B = A + 16777216;         //  8,388,608 floats (32 MB)
  float* C = B + 8388608;          //  8,388,608 floats (32 MB)

  const dim3 blk(256);
  const int N = 16;

  // --- Encoder ---
  conv4s2_row<3, 8, true, 128><<<dim3(64, 8, N), blk, 0, stream>>>(
      x, enc_w0, enc_b0, A, 128, 64);
  conv4s2_64v3<64, 16, true><<<dim3(16, 8, N), blk, 0, stream>>>(
      A, enc_w1, enc_b1, B, 128);
  conv3_64v3<128, 16, false, false><<<dim3(16, 8, N), blk, 0, stream>>>(
      B, enc_wf, enc_bf, C, 128);
  // enc res stack, ping-pong C -> B -> C
  res_block3<<<dim3(64, N), blk, 0, stream>>>(
      C, enc_res_w1, enc_res_b1, enc_res_w2, enc_res_b2, B);
  res_block3<<<dim3(64, N), blk, 0, stream>>>(
      B, enc_res_w1 + (size_t)32 * 128 * 9, enc_res_b1 + 32,
      enc_res_w2 + (size_t)128 * 32, enc_res_b2 + 128, C);
  // pre: relu(C) -> z in A
  conv1x1_kernel<128, 16, true, false><<<dim3(16, 4, N), blk, 0, stream>>>(
      C, pre_w, pre_b, A, 4096, 64);

  // --- VQ (in-place on A) ---
  vq_kernel2<<<dim3(1024), blk, 0, stream>>>(codebook, A);

  // --- Decoder ---
  conv3_64v3<64, 16, false, false><<<dim3(16, 8, N), blk, 0, stream>>>(
      A, dec_w, dec_b, B, 128);
  // dec res stack, ping-pong B -> C -> B
  res_block3<<<dim3(64, N), blk, 0, stream>>>(
      B, dec_res_w1, dec_res_b1, dec_res_w2, dec_res_b2, C);
  res_block3<<<dim3(64, N), blk, 0, stream>>>(
      C, dec_res_w1 + (size_t)32 * 128 * 9, dec_res_b1 + 32,
      dec_res_w2 + (size_t)128 * 32, dec_res_b2 + 128, B);
  // up0: relu(B) -> A(16,64,128,128), ReLU
  convt_64v3<128, 8, true, true><<<dim3(32, 8, N), blk, 0, stream>>>(
      B, up_w0, up_b0, A, 64, 64);
  // up1: A -> out(16,3,256,256)
  convt_row<64, 3, false, false, 128><<<dim3(128, 1, N), blk, 0, stream>>>(
      A, up_w1, up_b1, out, 128, 3);
}

// Round 7
// 2949.345 us; speedup vs baseline: 1.4420x; 1.0930x over previous
//
#include <hip/hip_runtime.h>
#include <math.h>

// -------------------------------------------------------------------------
// VQ-VAE forward, fp32, round 7:
//  - conv3_tile: LDS-staged 8-row x 64-col tile, vertical-pair outputs,
//    float4 staging, no shuffles. Used for convf, dec, all res 3x3.
//  - res unfused again: conv3_tile -> conv1x1(fused add), in-place h.
//  - up0 convt COT 16. conv0/conv1/pre/up1/VQ unchanged.
// Workspace: A(64MB) B(32MB) C(32MB) = 134.2 MB.
// -------------------------------------------------------------------------

#define DEV __device__ __forceinline__

DEV int rfl(int v) { return __builtin_amdgcn_readfirstlane(v); }

// ---------------- conv 4x4 stride2 pad1 (generic, used for conv0) ---------
template<int CIN, int COT, bool RELU_OUT, int OW>
__global__ __launch_bounds__(256) void conv4s2_row(
    const float* __restrict__ x, const float* __restrict__ w,
    const float* __restrict__ bias, float* __restrict__ y,
    int Hout, int Cout) {
  const int Win = OW * 2, Hin = Hout * 2;
  const int t = blockIdx.x * 256 + threadIdx.x;
  const int wo = t & (OW - 1);
  const int ho = rfl(t / OW);
  const int co0 = blockIdx.y * COT, n = blockIdx.z;

  float acc[COT];
#pragma unroll
  for (int u = 0; u < COT; u++) acc[u] = bias[co0 + u];

  const int iw0 = 2 * wo - 1;
  const int cA = iw0 < 0 ? 0 : iw0;
  const bool mA = iw0 >= 0;
  const int cD = (iw0 + 3 < Win) ? iw0 + 3 : Win - 1;
  const bool mD = iw0 + 3 < Win;

  for (int ci = 0; ci < CIN; ci++) {
    const float* xp = x + ((size_t)(n * CIN + ci)) * Hin * Win;
    const float* wp = w + ((size_t)(co0 * CIN + ci)) * 16;
#pragma unroll
    for (int kh = 0; kh < 4; kh++) {
      const int ih = 2 * ho - 1 + kh;
      if (ih >= 0 && ih < Hin) {
        const float* row = xp + (size_t)ih * Win;
        float x0 = row[cA];      x0 = mA ? x0 : 0.f;
        float x1 = row[iw0 + 1];
        float x2 = row[iw0 + 2];
        float x3 = row[cD];      x3 = mD ? x3 : 0.f;
#pragma unroll
        for (int u = 0; u < COT; u++) {
          const float* wr = wp + u * CIN * 16 + kh * 4;
          acc[u] = fmaf(x0, wr[0], acc[u]);
          acc[u] = fmaf(x1, wr[1], acc[u]);
          acc[u] = fmaf(x2, wr[2], acc[u]);
          acc[u] = fmaf(x3, wr[3], acc[u]);
        }
      }
    }
  }
#pragma unroll
  for (int u = 0; u < COT; u++) {
    float v = acc[u];
    if (RELU_OUT) v = fmaxf(v, 0.f);
    y[(((size_t)(n * Cout + co0 + u)) * Hout + ho) * OW + wo] = v;
  }
}

// ---------------- conv 4x4 s2 p1, 128x128 -> 64x64, shuffle+prefetch ------
template<int CIN, int COT, bool RELU_OUT>
__global__ __launch_bounds__(256) void conv4s2_64v3(
    const float* __restrict__ x, const float* __restrict__ w,
    const float* __restrict__ bias, float* __restrict__ y, int Cout) {
  const int lane = threadIdx.x & 63;
  const int ho = rfl(blockIdx.x * 4 + (threadIdx.x >> 6));
  const int co0 = blockIdx.y * COT, n = blockIdx.z;

  float acc[COT];
#pragma unroll
  for (int u = 0; u < COT; u++) acc[u] = bias[co0 + u];

  int ro[4]; bool rv[4];
#pragma unroll
  for (int kh = 0; kh < 4; kh++) {
    const int ih = 2 * ho - 1 + kh;
    rv[kh] = (ih >= 0 && ih < 128);
    ro[kh] = (rv[kh] ? ih : 0) * 128;
  }
  const float* xb = x + ((size_t)(n * CIN)) * 16384;

  float2 p[4];
#pragma unroll
  for (int kh = 0; kh < 4; kh++)
    p[kh] = ((const float2*)(xb + ro[kh]))[lane];

  for (int ci = 0; ci < CIN; ci++) {
    float2 c[4];
#pragma unroll
    for (int kh = 0; kh < 4; kh++) {
      c[kh].x = rv[kh] ? p[kh].x : 0.f;
      c[kh].y = rv[kh] ? p[kh].y : 0.f;
    }
    const int cn = (ci < CIN - 1 ? ci + 1 : ci) * 16384;
#pragma unroll
    for (int kh = 0; kh < 4; kh++)
      p[kh] = ((const float2*)(xb + cn + ro[kh]))[lane];

    const float* wp = w + ((size_t)(co0 * CIN + ci)) * 16;
#pragma unroll
    for (int kh = 0; kh < 4; kh++) {
      const float e = c[kh].x, o = c[kh].y;
      float xm = __shfl_up(o, 1);   xm = lane > 0  ? xm : 0.f;
      float xp = __shfl_down(e, 1); xp = lane < 63 ? xp : 0.f;
#pragma unroll
      for (int u = 0; u < COT; u++) {
        const float* wr = wp + u * CIN * 16 + kh * 4;
        acc[u] = fmaf(xm, wr[0], acc[u]);
        acc[u] = fmaf(e,  wr[1], acc[u]);
        acc[u] = fmaf(o,  wr[2], acc[u]);
        acc[u] = fmaf(xp, wr[3], acc[u]);
      }
    }
  }
#pragma unroll
  for (int u = 0; u < COT; u++) {
    float v = acc[u];
    if (RELU_OUT) v = fmaxf(v, 0.f);
    y[(((size_t)(n * Cout + co0 + u)) * 64 + ho) * 64 + lane] = v;
  }
}

// ---------------- conv 3x3 s1 p1 on 64x64, LDS tile, vertical pairs -------
// Block 256 = 4 waves; wave w computes output rows r0+2w, r0+2w+1 for COT
// out-channels. Input staged in 8-ci chunks of 10 rows (r0-1..r0+8), float4.
template<int CIN, int COT, bool RELU_IN, bool RELU_OUT>
__global__ __launch_bounds__(256) void conv3_tile(
    const float* __restrict__ x, const float* __restrict__ w,
    const float* __restrict__ bias, float* __restrict__ y, int Cout) {
  constexpr int CHUNK = 8;
  __shared__ float xs[CHUNK * 10 * 64];   // [ci][row][col], 20 KB
  const int lane = threadIdx.x & 63;
  const int wv = threadIdx.x >> 6;        // 0..3
  const int r0 = blockIdx.x * 8;
  const int co0 = blockIdx.y * COT;
  const int n = blockIdx.z;

  float acc0[COT], acc1[COT];
#pragma unroll
  for (int u = 0; u < COT; u++) { acc0[u] = bias[co0 + u]; acc1[u] = bias[co0 + u]; }

  const int lm = lane > 0 ? lane - 1 : 0;
  const bool mm = lane > 0;
  const int lp = lane < 63 ? lane + 1 : 63;
  const bool mp = lane < 63;

  const float* xn = x + ((size_t)(n * CIN)) * 4096;

  for (int c0 = 0; c0 < CIN; c0 += CHUNK) {
    __syncthreads();
    // stage CHUNK ci x 10 rows x 64 cols (zero-fill OOB rows), float4
    for (int q = threadIdx.x; q < CHUNK * 160; q += 256) {
      const int ci = q / 160, rem = q - ci * 160;
      const int rr = rem >> 4, f4 = rem & 15;
      const int grow = r0 - 1 + rr;
      float4 v = make_float4(0.f, 0.f, 0.f, 0.f);
      if ((unsigned)grow < 64u)
        v = *(const float4*)(xn + ((size_t)(c0 + ci)) * 4096 + (grow << 6) + (f4 << 2));
      *(float4*)&xs[(ci * 10 + rr) * 64 + (f4 << 2)] = v;
    }
    __syncthreads();
#pragma unroll
    for (int ci = 0; ci < CHUNK; ci++) {
      float a[4], v[4], b[4];
#pragma unroll
      for (int d = 0; d < 4; d++) {
        const float* rowp = &xs[(ci * 10 + (wv << 1) + d) * 64];
        float aa = rowp[lm]; aa = mm ? aa : 0.f;
        float vv = rowp[lane];
        float bb = rowp[lp]; bb = mp ? bb : 0.f;
        if (RELU_IN) { aa = fmaxf(aa, 0.f); vv = fmaxf(vv, 0.f); bb = fmaxf(bb, 0.f); }
        a[d] = aa; v[d] = vv; b[d] = bb;
      }
      const float* wb = w + ((size_t)(co0 * CIN + c0 + ci)) * 9;
#pragma unroll
      for (int u = 0; u < COT; u++) {
        const float* wr = wb + u * CIN * 9;     // uniform -> s_load
#pragma unroll
        for (int kh = 0; kh < 3; kh++) {
          acc0[u] = fmaf(a[kh],     wr[kh * 3 + 0], acc0[u]);
          acc0[u] = fmaf(v[kh],     wr[kh * 3 + 1], acc0[u]);
          acc0[u] = fmaf(b[kh],     wr[kh * 3 + 2], acc0[u]);
          acc1[u] = fmaf(a[kh + 1], wr[kh * 3 + 0], acc1[u]);
          acc1[u] = fmaf(v[kh + 1], wr[kh * 3 + 1], acc1[u]);
          acc1[u] = fmaf(b[kh + 1], wr[kh * 3 + 2], acc1[u]);
        }
      }
    }
  }
  const int ro = r0 + (wv << 1);
#pragma unroll
  for (int u = 0; u < COT; u++) {
    float v0 = acc0[u], v1 = acc1[u];
    if (RELU_OUT) { v0 = fmaxf(v0, 0.f); v1 = fmaxf(v1, 0.f); }
    float* yp = y + (((size_t)(n * Cout + co0 + u)) * 64 + ro) * 64 + lane;
    yp[0] = v0;
    yp[64] = v1;
  }
}

// ---------------- conv 1x1 (ACCUM: y += b + conv, residual fused) ---------
template<int CIN, int COT, bool RELU_IN, bool ACCUM>
__global__ __launch_bounds__(256) void conv1x1_kernel(
    const float* __restrict__ x, const float* __restrict__ w,
    const float* __restrict__ bias, float* __restrict__ y,
    int HW, int Cout) {
  const int t = blockIdx.x * 256 + threadIdx.x;
  const int cog = blockIdx.y, n = blockIdx.z;
  const int co0 = cog * COT;

  float acc[COT];
#pragma unroll
  for (int u = 0; u < COT; u++) acc[u] = bias[co0 + u];

  for (int ci = 0; ci < CIN; ci++) {
    float xv = x[((size_t)(n * CIN + ci)) * HW + t];
    if (RELU_IN) xv = fmaxf(xv, 0.f);
#pragma unroll
    for (int u = 0; u < COT; u++)
      acc[u] = fmaf(xv, w[(co0 + u) * CIN + ci], acc[u]);
  }
#pragma unroll
  for (int u = 0; u < COT; u++) {
    size_t idx = ((size_t)(n * Cout + co0 + u)) * HW + t;
    if (ACCUM) y[idx] = y[idx] + acc[u];
    else       y[idx] = acc[u];
  }
}

// ---------------- ConvTranspose 4x4 s2 p1, WH=64, shuffle+prefetch --------
template<int CIN, int COT, bool RELU_IN, bool RELU_OUT>
__global__ __launch_bounds__(256) void convt_64v3(
    const float* __restrict__ x, const float* __restrict__ w,
    const float* __restrict__ bias, float* __restrict__ y,
    int Hin, int Cout) {
  const int Hout = Hin * 2;
  const int a = threadIdx.x & 63;
  const int oh = rfl(blockIdx.x * 4 + (threadIdx.x >> 6));
  const int co0 = blockIdx.y * COT, n = blockIdx.z;

  float acc0[COT], acc1[COT];
#pragma unroll
  for (int u = 0; u < COT; u++) { acc0[u] = bias[co0 + u]; acc1[u] = bias[co0 + u]; }

  const int kh0 = (oh + 1) & 1;
#pragma unroll
  for (int dh = 0; dh < 2; dh++) {
    const int kh = kh0 + 2 * dh;
    const int ih = (oh + 1 - kh) >> 1;
    if (ih >= 0 && ih < Hin) {               // uniform
      const float* xb = x + (((size_t)(n * CIN)) * Hin + ih) * 64 + a;
      float p = xb[0];
      for (int ci = 0; ci < CIN; ci++) {
        float x0 = p;
        if (RELU_IN) x0 = fmaxf(x0, 0.f);
        p = xb[(ci < CIN - 1 ? ci + 1 : ci) * Hin * 64];
        float xm1 = __shfl_up(x0, 1);   xm1 = a > 0  ? xm1 : 0.f;
        float xp1 = __shfl_down(x0, 1); xp1 = a < 63 ? xp1 : 0.f;
        const float* wp = w + ((size_t)(ci * Cout + co0)) * 16 + kh * 4;
#pragma unroll
        for (int u = 0; u < COT; u++) {
          const float* wr = wp + u * 16;
          acc0[u] = fmaf(x0,  wr[1], acc0[u]);
          acc0[u] = fmaf(xm1, wr[3], acc0[u]);
          acc1[u] = fmaf(xp1, wr[0], acc1[u]);
          acc1[u] = fmaf(x0,  wr[2], acc1[u]);
        }
      }
    }
  }
#pragma unroll
  for (int u = 0; u < COT; u++) {
    float v0 = acc0[u], v1 = acc1[u];
    if (RELU_OUT) { v0 = fmaxf(v0, 0.f); v1 = fmaxf(v1, 0.f); }
    float* row = y + (((size_t)(n * Cout + co0 + u)) * Hout + oh) * 128;
    ((float2*)row)[a] = make_float2(v0, v1);
  }
}

// ---------------- ConvTranspose 4x4 s2 p1 (generic, used for up1) ---------
template<int CIN, int COT, bool RELU_IN, bool RELU_OUT, int WH>
__global__ __launch_bounds__(256) void convt_row(
    const float* __restrict__ x, const float* __restrict__ w,
    const float* __restrict__ bias, float* __restrict__ y,
    int Hin, int Cout) {
  const int Hout = Hin * 2;
  const int t = blockIdx.x * 256 + threadIdx.x;
  const int a = t & (WH - 1);
  const int oh = rfl(t / WH);
  const int co0 = blockIdx.y * COT, n = blockIdx.z;

  float acc0[COT], acc1[COT];
#pragma unroll
  for (int u = 0; u < COT; u++) { acc0[u] = bias[co0 + u]; acc1[u] = bias[co0 + u]; }

  const int cm = a > 0 ? a - 1 : 0;
  const bool mm = a > 0;
  const int cp = a < WH - 1 ? a + 1 : WH - 1;
  const bool mp = a < WH - 1;

  const int kh0 = (oh + 1) & 1;
#pragma unroll
  for (int dh = 0; dh < 2; dh++) {
    const int kh = kh0 + 2 * dh;
    const int ih = (oh + 1 - kh) >> 1;
    if (ih >= 0 && ih < Hin) {
      for (int ci = 0; ci < CIN; ci++) {
        const float* row = x + (((size_t)(n * CIN + ci)) * Hin + ih) * WH;
        float x0  = row[a];
        float xm1 = row[cm];  xm1 = mm ? xm1 : 0.f;
        float xp1 = row[cp];  xp1 = mp ? xp1 : 0.f;
        if (RELU_IN) {
          x0 = fmaxf(x0, 0.f); xm1 = fmaxf(xm1, 0.f); xp1 = fmaxf(xp1, 0.f);
        }
        const float* wp = w + ((size_t)(ci * Cout + co0)) * 16 + kh * 4;
#pragma unroll
        for (int u = 0; u < COT; u++) {
          const float* wr = wp + u * 16;
          acc0[u] = fmaf(x0,  wr[1], acc0[u]);
          acc0[u] = fmaf(xm1, wr[3], acc0[u]);
          acc1[u] = fmaf(xp1, wr[0], acc1[u]);
          acc1[u] = fmaf(x0,  wr[2], acc1[u]);
        }
      }
    }
  }
#pragma unroll
  for (int u = 0; u < COT; u++) {
    float v0 = acc0[u], v1 = acc1[u];
    if (RELU_OUT) { v0 = fmaxf(v0, 0.f); v1 = fmaxf(v1, 0.f); }
    float* row = y + (((size_t)(n * Cout + co0 + u)) * Hout + oh) * (2 * WH);
    ((float2*)row)[a] = make_float2(v0, v1);
  }
}

// ---------------- Vector quantizer v2 (in-place, fp64, code-split) --------
__global__ __launch_bounds__(256) void vq_kernel2(
    const float* __restrict__ cb, float* __restrict__ zq) {
  __shared__ float cbs[64 * 64];
  __shared__ double cbn[512];
  __shared__ double redD[256];
  __shared__ int    redI[256];
  __shared__ int    bestIdx[64];
  const int tid = threadIdx.x;
  const int lane = tid & 63, g = tid >> 6;
  const int n = blockIdx.x >> 6, row = blockIdx.x & 63;
  const int hw = (row << 6) | lane;
  float* zp = zq + ((size_t)n) * 64 * 4096 + hw;
  float zr[64];
#pragma unroll
  for (int d = 0; d < 64; d++) zr[d] = zp[(size_t)d * 4096];

  for (int k = tid; k < 512; k += 256) {
    double s = 0.0;
    for (int d = 0; d < 64; d++) {
      double c = (double)cb[d * 512 + k];
      s = fma(c, c, s);
    }
    cbn[k] = s;
  }

  int best = 0;
  double bestd = 1e300;
  for (int kt = 0; kt < 8; kt++) {
    __syncthreads();
    for (int i = tid; i < 4096; i += 256) {
      int d = i >> 6, kk = i & 63;
      cbs[i] = cb[d * 512 + kt * 64 + kk];
    }
    __syncthreads();
#pragma unroll 1
    for (int j = 0; j < 16; j++) {
      const int kk = g * 16 + j;
      double d0 = 0.0, d1 = 0.0, d2 = 0.0, d3 = 0.0;
#pragma unroll
      for (int d = 0; d < 64; d += 4) {
        d0 = fma((double)zr[d],     (double)cbs[(d)     * 64 + kk], d0);
        d1 = fma((double)zr[d + 1], (double)cbs[(d + 1) * 64 + kk], d1);
        d2 = fma((double)zr[d + 2], (double)cbs[(d + 2) * 64 + kk], d2);
        d3 = fma((double)zr[d + 3], (double)cbs[(d + 3) * 64 + kk], d3);
      }
      const int k = kt * 64 + kk;
      double dist = cbn[k] - 2.0 * ((d0 + d1) + (d2 + d3));
      if (dist < bestd) { bestd = dist; best = k; }
    }
  }
  redD[tid] = bestd;
  redI[tid] = best;
  __syncthreads();
  if (g == 0) {
    double bd = redD[lane];
    int bi = redI[lane];
#pragma unroll
    for (int gg = 1; gg < 4; gg++) {
      double d2 = redD[gg * 64 + lane];
      int i2 = redI[gg * 64 + lane];
      if (d2 < bd || (d2 == bd && i2 < bi)) { bd = d2; bi = i2; }
    }
    bestIdx[lane] = bi;
  }
  __syncthreads();
  const int k = bestIdx[lane];
#pragma unroll
  for (int j = 0; j < 16; j++) {
    const int d = g * 16 + j;
    zp[(size_t)d * 4096] = cb[d * 512 + k];
  }
}

// -------------------------------------------------------------------------
extern "C" void kernel_launch(void* const* d_in, const int* in_sizes, int n_in,
                              void* d_out, int out_size, void* d_ws, size_t ws_size,
                              hipStream_t stream) {
  const float* x          = (const float*)d_in[0];
  const float* enc_w0     = (const float*)d_in[1];
  const float* enc_b0     = (const float*)d_in[2];
  const float* enc_w1     = (const float*)d_in[3];
  const float* enc_b1     = (const float*)d_in[4];
  const float* enc_wf     = (const float*)d_in[5];
  const float* enc_bf     = (const float*)d_in[6];
  const float* enc_res_w1 = (const float*)d_in[7];
  const float* enc_res_b1 = (const float*)d_in[8];
  const float* enc_res_w2 = (const float*)d_in[9];
  const float* enc_res_b2 = (const float*)d_in[10];
  const float* pre_w      = (const float*)d_in[11];
  const float* pre_b      = (const float*)d_in[12];
  const float* codebook   = (const float*)d_in[13];
  const float* dec_w      = (const float*)d_in[14];
  const float* dec_b      = (const float*)d_in[15];
  const float* dec_res_w1 = (const float*)d_in[16];
  const float* dec_res_b1 = (const float*)d_in[17];
  const float* dec_res_w2 = (const float*)d_in[18];
  const float* dec_res_b2 = (const float*)d_in[19];
  const float* up_w0      = (const float*)d_in[20];
  const float* up_b0      = (const float*)d_in[21];
  const float* up_w1      = (const float*)d_in[22];
  const float* up_b1      = (const float*)d_in[23];
  float* out = (float*)d_out;

  float* A = (float*)d_ws;         // 16,777,216 floats (64 MB)
  float* B = A + 16777216;         //  8,388,608 floats (32 MB)
  float* C = B + 8388608;          //  8,388,608 floats (32 MB)

  const dim3 blk(256);
  const int N = 16;

  // --- Encoder ---
  conv4s2_row<3, 8, true, 128><<<dim3(64, 8, N), blk, 0, stream>>>(
      x, enc_w0, enc_b0, A, 128, 64);
  conv4s2_64v3<64, 16, true><<<dim3(16, 8, N), blk, 0, stream>>>(
      A, enc_w1, enc_b1, B, 128);
  conv3_tile<128, 16, false, false><<<dim3(8, 8, N), blk, 0, stream>>>(
      B, enc_wf, enc_bf, C, 128);
  // enc res stack on C: 3x3 -> mid in A, fused 1x1-add in-place on C
  for (int i = 0; i < 2; i++) {
    conv3_tile<128, 8, true, false><<<dim3(8, 4, N), blk, 0, stream>>>(
        C, enc_res_w1 + (size_t)i * 32 * 128 * 9, enc_res_b1 + i * 32, A, 32);
    conv1x1_kernel<32, 8, true, true><<<dim3(16, 16, N), blk, 0, stream>>>(
        A, enc_res_w2 + (size_t)i * 128 * 32, enc_res_b2 + i * 128, C, 4096, 128);
  }
  // pre: relu(C) -> z in A
  conv1x1_kernel<128, 16, true, false><<<dim3(16, 4, N), blk, 0, stream>>>(
      C, pre_w, pre_b, A, 4096, 64);

  // --- VQ (in-place on A) ---
  vq_kernel2<<<dim3(1024), blk, 0, stream>>>(codebook, A);

  // --- Decoder ---
  conv3_tile<64, 16, false, false><<<dim3(8, 8, N), blk, 0, stream>>>(
      A, dec_w, dec_b, B, 128);
  // dec res stack on B: 3x3 -> mid in A (free), fused 1x1-add in-place on B
  for (int i = 0; i < 2; i++) {
    conv3_tile<128, 8, true, false><<<dim3(8, 4, N), blk, 0, stream>>>(
        B, dec_res_w1 + (size_t)i * 32 * 128 * 9, dec_res_b1 + i * 32, A, 32);
    conv1x1_kernel<32, 8, true, true><<<dim3(16, 16, N), blk, 0, stream>>>(
        A, dec_res_w2 + (size_t)i * 128 * 32, dec_res_b2 + i * 128, B, 4096, 128);
  }
  // up0: relu(B) -> A(16,64,128,128), ReLU
  convt_64v3<128, 16, true, true><<<dim3(32, 4, N), blk, 0, stream>>>(
      B, up_w0, up_b0, A, 64, 64);
  // up1: A -> out(16,3,256,256)
  convt_row<64, 3, false, false, 128><<<dim3(128, 1, N), blk, 0, stream>>>(
      A, up_w1, up_b1, out, 128, 3);
}

// Round 8
// 2685.938 us; speedup vs baseline: 1.5834x; 1.0981x over previous
//
#include <hip/hip_runtime.h>
#include <math.h>

// -------------------------------------------------------------------------
// VQ-VAE forward, fp32, round 8:
//  - conv3_tile2: 4-row/128-thread blocks (8 blocks/CU), register
//    double-buffered staging, zero-padded LDS cols (aligned b128, no masks).
//  - VQ v3: codebook pre-converted to fp64 in workspace, scalar (s_load)
//    codebook reads, no LDS tile, no per-FMA cvt. Exact first-min kept.
//  - conv1x1 v4: float4 x 4 positions per thread.
//  - conv0 COT 16. conv1/up0/up1 unchanged from R7.
// Workspace: A(64MB) B(32MB) C(32MB); cb64/cbn64 carved from A's free tail.
// -------------------------------------------------------------------------

#define DEV __device__ __forceinline__

DEV int rfl(int v) { return __builtin_amdgcn_readfirstlane(v); }

// ---------------- conv 4x4 stride2 pad1 (generic, used for conv0) ---------
template<int CIN, int COT, bool RELU_OUT, int OW>
__global__ __launch_bounds__(256) void conv4s2_row(
    const float* __restrict__ x, const float* __restrict__ w,
    const float* __restrict__ bias, float* __restrict__ y,
    int Hout, int Cout) {
  const int Win = OW * 2, Hin = Hout * 2;
  const int t = blockIdx.x * 256 + threadIdx.x;
  const int wo = t & (OW - 1);
  const int ho = rfl(t / OW);
  const int co0 = blockIdx.y * COT, n = blockIdx.z;

  float acc[COT];
#pragma unroll
  for (int u = 0; u < COT; u++) acc[u] = bias[co0 + u];

  const int iw0 = 2 * wo - 1;
  const int cA = iw0 < 0 ? 0 : iw0;
  const bool mA = iw0 >= 0;
  const int cD = (iw0 + 3 < Win) ? iw0 + 3 : Win - 1;
  const bool mD = iw0 + 3 < Win;

  for (int ci = 0; ci < CIN; ci++) {
    const float* xp = x + ((size_t)(n * CIN + ci)) * Hin * Win;
    const float* wp = w + ((size_t)(co0 * CIN + ci)) * 16;
#pragma unroll
    for (int kh = 0; kh < 4; kh++) {
      const int ih = 2 * ho - 1 + kh;
      if (ih >= 0 && ih < Hin) {
        const float* row = xp + (size_t)ih * Win;
        float x0 = row[cA];      x0 = mA ? x0 : 0.f;
        float x1 = row[iw0 + 1];
        float x2 = row[iw0 + 2];
        float x3 = row[cD];      x3 = mD ? x3 : 0.f;
#pragma unroll
        for (int u = 0; u < COT; u++) {
          const float* wr = wp + u * CIN * 16 + kh * 4;
          acc[u] = fmaf(x0, wr[0], acc[u]);
          acc[u] = fmaf(x1, wr[1], acc[u]);
          acc[u] = fmaf(x2, wr[2], acc[u]);
          acc[u] = fmaf(x3, wr[3], acc[u]);
        }
      }
    }
  }
#pragma unroll
  for (int u = 0; u < COT; u++) {
    float v = acc[u];
    if (RELU_OUT) v = fmaxf(v, 0.f);
    y[(((size_t)(n * Cout + co0 + u)) * Hout + ho) * OW + wo] = v;
  }
}

// ---------------- conv 4x4 s2 p1, 128x128 -> 64x64, shuffle+prefetch ------
template<int CIN, int COT, bool RELU_OUT>
__global__ __launch_bounds__(256) void conv4s2_64v3(
    const float* __restrict__ x, const float* __restrict__ w,
    const float* __restrict__ bias, float* __restrict__ y, int Cout) {
  const int lane = threadIdx.x & 63;
  const int ho = rfl(blockIdx.x * 4 + (threadIdx.x >> 6));
  const int co0 = blockIdx.y * COT, n = blockIdx.z;

  float acc[COT];
#pragma unroll
  for (int u = 0; u < COT; u++) acc[u] = bias[co0 + u];

  int ro[4]; bool rv[4];
#pragma unroll
  for (int kh = 0; kh < 4; kh++) {
    const int ih = 2 * ho - 1 + kh;
    rv[kh] = (ih >= 0 && ih < 128);
    ro[kh] = (rv[kh] ? ih : 0) * 128;
  }
  const float* xb = x + ((size_t)(n * CIN)) * 16384;

  float2 p[4];
#pragma unroll
  for (int kh = 0; kh < 4; kh++)
    p[kh] = ((const float2*)(xb + ro[kh]))[lane];

  for (int ci = 0; ci < CIN; ci++) {
    float2 c[4];
#pragma unroll
    for (int kh = 0; kh < 4; kh++) {
      c[kh].x = rv[kh] ? p[kh].x : 0.f;
      c[kh].y = rv[kh] ? p[kh].y : 0.f;
    }
    const int cn = (ci < CIN - 1 ? ci + 1 : ci) * 16384;
#pragma unroll
    for (int kh = 0; kh < 4; kh++)
      p[kh] = ((const float2*)(xb + cn + ro[kh]))[lane];

    const float* wp = w + ((size_t)(co0 * CIN + ci)) * 16;
#pragma unroll
    for (int kh = 0; kh < 4; kh++) {
      const float e = c[kh].x, o = c[kh].y;
      float xm = __shfl_up(o, 1);   xm = lane > 0  ? xm : 0.f;
      float xp = __shfl_down(e, 1); xp = lane < 63 ? xp : 0.f;
#pragma unroll
      for (int u = 0; u < COT; u++) {
        const float* wr = wp + u * CIN * 16 + kh * 4;
        acc[u] = fmaf(xm, wr[0], acc[u]);
        acc[u] = fmaf(e,  wr[1], acc[u]);
        acc[u] = fmaf(o,  wr[2], acc[u]);
        acc[u] = fmaf(xp, wr[3], acc[u]);
      }
    }
  }
#pragma unroll
  for (int u = 0; u < COT; u++) {
    float v = acc[u];
    if (RELU_OUT) v = fmaxf(v, 0.f);
    y[(((size_t)(n * Cout + co0 + u)) * 64 + ho) * 64 + lane] = v;
  }
}

// ---------------- conv 3x3 s1 p1 on 64x64, tile v2 ------------------------
// 4 output rows per block, 128 threads (2 waves of vertical pairs).
// Register double-buffered 8-ci chunks; LDS rows padded: data cols 4..67,
// zero cols 3 and 68 (no edge masks, aligned float4 staging).
template<int CIN, int COT, bool RELU_IN>
__global__ __launch_bounds__(128) void conv3_tile2(
    const float* __restrict__ x, const float* __restrict__ w,
    const float* __restrict__ bias, float* __restrict__ y, int Cout) {
  constexpr int CHUNK = 8;
  constexpr int RS = 72;                 // padded LDS row stride (floats)
  __shared__ float xs[CHUNK * 6 * RS];   // 13.8 KB
  const int tid = threadIdx.x;
  const int lane = tid & 63;
  const int wv = rfl(tid >> 6);          // 0..1
  const int r0 = blockIdx.x * 4;
  const int co0 = blockIdx.y * COT;
  const int n = blockIdx.z;

  // zero pad columns once (never overwritten)
  for (int q = tid; q < CHUNK * 6 * 2; q += 128) {
    const int row = q >> 1;
    xs[row * RS + ((q & 1) ? 68 : 3)] = 0.f;
  }

  // per-thread staging slots (constant across chunks)
  int lofs[6]; int gofs[6]; bool gval[6];
#pragma unroll
  for (int i = 0; i < 6; i++) {
    const int q = tid + i * 128;
    const int ci = q / 96, rem = q - ci * 96;
    const int rr = rem >> 4, f4 = rem & 15;
    const int grow = r0 - 1 + rr;
    gval[i] = (unsigned)grow < 64u;
    gofs[i] = ci * 4096 + (gval[i] ? grow : 0) * 64 + f4 * 4;
    lofs[i] = (ci * 6 + rr) * RS + 4 + f4 * 4;
  }

  const float* xn = x + ((size_t)(n * CIN)) * 4096;

  float4 pf[6];
#pragma unroll
  for (int i = 0; i < 6; i++) {
    float4 v = *(const float4*)(xn + gofs[i]);
    if (!gval[i]) v = make_float4(0.f, 0.f, 0.f, 0.f);
    if (RELU_IN) {
      v.x = fmaxf(v.x, 0.f); v.y = fmaxf(v.y, 0.f);
      v.z = fmaxf(v.z, 0.f); v.w = fmaxf(v.w, 0.f);
    }
    pf[i] = v;
  }

  float acc0[COT], acc1[COT];
#pragma unroll
  for (int u = 0; u < COT; u++) { acc0[u] = bias[co0 + u]; acc1[u] = bias[co0 + u]; }

  const int colC = 4 + lane;

  for (int c0 = 0; c0 < CIN; c0 += CHUNK) {
    __syncthreads();
#pragma unroll
    for (int i = 0; i < 6; i++) *(float4*)&xs[lofs[i]] = pf[i];
    __syncthreads();
    if (c0 + CHUNK < CIN) {
      const float* xc = xn + (size_t)(c0 + CHUNK) * 4096;
#pragma unroll
      for (int i = 0; i < 6; i++) {
        float4 v = *(const float4*)(xc + gofs[i]);
        if (!gval[i]) v = make_float4(0.f, 0.f, 0.f, 0.f);
        if (RELU_IN) {
          v.x = fmaxf(v.x, 0.f); v.y = fmaxf(v.y, 0.f);
          v.z = fmaxf(v.z, 0.f); v.w = fmaxf(v.w, 0.f);
        }
        pf[i] = v;
      }
    }
#pragma unroll
    for (int ci = 0; ci < CHUNK; ci++) {
      float a[4], v[4], b[4];
#pragma unroll
      for (int d = 0; d < 4; d++) {
        const float* rp = &xs[(ci * 6 + wv * 2 + d) * RS];
        a[d] = rp[colC - 1];
        v[d] = rp[colC];
        b[d] = rp[colC + 1];
      }
      const float* wb = w + ((size_t)(co0 * CIN + c0 + ci)) * 9;
#pragma unroll
      for (int u = 0; u < COT; u++) {
        const float* wr = wb + u * CIN * 9;      // uniform -> s_load
#pragma unroll
        for (int kh = 0; kh < 3; kh++) {
          acc0[u] = fmaf(a[kh],     wr[kh * 3 + 0], acc0[u]);
          acc0[u] = fmaf(v[kh],     wr[kh * 3 + 1], acc0[u]);
          acc0[u] = fmaf(b[kh],     wr[kh * 3 + 2], acc0[u]);
          acc1[u] = fmaf(a[kh + 1], wr[kh * 3 + 0], acc1[u]);
          acc1[u] = fmaf(v[kh + 1], wr[kh * 3 + 1], acc1[u]);
          acc1[u] = fmaf(b[kh + 1], wr[kh * 3 + 2], acc1[u]);
        }
      }
    }
  }
  const int ro = r0 + (wv << 1);
#pragma unroll
  for (int u = 0; u < COT; u++) {
    float* yp = y + (((size_t)(n * Cout + co0 + u)) * 64 + ro) * 64 + lane;
    yp[0]  = acc0[u];
    yp[64] = acc1[u];
  }
}

// ---------------- conv 1x1 v4: 4 positions per thread ---------------------
template<int CIN, int COT, bool RELU_IN, bool ACCUM>
__global__ __launch_bounds__(256) void conv1x1_v4(
    const float* __restrict__ x, const float* __restrict__ w,
    const float* __restrict__ bias, float* __restrict__ y,
    int HW, int Cout) {
  const int p = (blockIdx.x * 256 + threadIdx.x) * 4;
  const int co0 = blockIdx.y * COT, n = blockIdx.z;

  float4 acc[COT];
#pragma unroll
  for (int u = 0; u < COT; u++) {
    const float b = bias[co0 + u];
    acc[u] = make_float4(b, b, b, b);
  }
  for (int ci = 0; ci < CIN; ci++) {
    float4 xv = *(const float4*)&x[((size_t)(n * CIN + ci)) * HW + p];
    if (RELU_IN) {
      xv.x = fmaxf(xv.x, 0.f); xv.y = fmaxf(xv.y, 0.f);
      xv.z = fmaxf(xv.z, 0.f); xv.w = fmaxf(xv.w, 0.f);
    }
#pragma unroll
    for (int u = 0; u < COT; u++) {
      const float wv = w[(co0 + u) * CIN + ci];
      acc[u].x = fmaf(xv.x, wv, acc[u].x);
      acc[u].y = fmaf(xv.y, wv, acc[u].y);
      acc[u].z = fmaf(xv.z, wv, acc[u].z);
      acc[u].w = fmaf(xv.w, wv, acc[u].w);
    }
  }
#pragma unroll
  for (int u = 0; u < COT; u++) {
    float4* yp = (float4*)&y[((size_t)(n * Cout + co0 + u)) * HW + p];
    if (ACCUM) {
      float4 h = *yp;
      h.x += acc[u].x; h.y += acc[u].y; h.z += acc[u].z; h.w += acc[u].w;
      *yp = h;
    } else {
      *yp = acc[u];
    }
  }
}

// ---------------- ConvTranspose 4x4 s2 p1, WH=64, shuffle+prefetch --------
template<int CIN, int COT, bool RELU_IN, bool RELU_OUT>
__global__ __launch_bounds__(256) void convt_64v3(
    const float* __restrict__ x, const float* __restrict__ w,
    const float* __restrict__ bias, float* __restrict__ y,
    int Hin, int Cout) {
  const int Hout = Hin * 2;
  const int a = threadIdx.x & 63;
  const int oh = rfl(blockIdx.x * 4 + (threadIdx.x >> 6));
  const int co0 = blockIdx.y * COT, n = blockIdx.z;

  float acc0[COT], acc1[COT];
#pragma unroll
  for (int u = 0; u < COT; u++) { acc0[u] = bias[co0 + u]; acc1[u] = bias[co0 + u]; }

  const int kh0 = (oh + 1) & 1;
#pragma unroll
  for (int dh = 0; dh < 2; dh++) {
    const int kh = kh0 + 2 * dh;
    const int ih = (oh + 1 - kh) >> 1;
    if (ih >= 0 && ih < Hin) {               // uniform
      const float* xb = x + (((size_t)(n * CIN)) * Hin + ih) * 64 + a;
      float p = xb[0];
      for (int ci = 0; ci < CIN; ci++) {
        float x0 = p;
        if (RELU_IN) x0 = fmaxf(x0, 0.f);
        p = xb[(ci < CIN - 1 ? ci + 1 : ci) * Hin * 64];
        float xm1 = __shfl_up(x0, 1);   xm1 = a > 0  ? xm1 : 0.f;
        float xp1 = __shfl_down(x0, 1); xp1 = a < 63 ? xp1 : 0.f;
        const float* wp = w + ((size_t)(ci * Cout + co0)) * 16 + kh * 4;
#pragma unroll
        for (int u = 0; u < COT; u++) {
          const float* wr = wp + u * 16;
          acc0[u] = fmaf(x0,  wr[1], acc0[u]);
          acc0[u] = fmaf(xm1, wr[3], acc0[u]);
          acc1[u] = fmaf(xp1, wr[0], acc1[u]);
          acc1[u] = fmaf(x0,  wr[2], acc1[u]);
        }
      }
    }
  }
#pragma unroll
  for (int u = 0; u < COT; u++) {
    float v0 = acc0[u], v1 = acc1[u];
    if (RELU_OUT) { v0 = fmaxf(v0, 0.f); v1 = fmaxf(v1, 0.f); }
    float* row = y + (((size_t)(n * Cout + co0 + u)) * Hout + oh) * 128;
    ((float2*)row)[a] = make_float2(v0, v1);
  }
}

// ---------------- ConvTranspose 4x4 s2 p1 (generic, used for up1) ---------
template<int CIN, int COT, bool RELU_IN, bool RELU_OUT, int WH>
__global__ __launch_bounds__(256) void convt_row(
    const float* __restrict__ x, const float* __restrict__ w,
    const float* __restrict__ bias, float* __restrict__ y,
    int Hin, int Cout) {
  const int Hout = Hin * 2;
  const int t = blockIdx.x * 256 + threadIdx.x;
  const int a = t & (WH - 1);
  const int oh = rfl(t / WH);
  const int co0 = blockIdx.y * COT, n = blockIdx.z;

  float acc0[COT], acc1[COT];
#pragma unroll
  for (int u = 0; u < COT; u++) { acc0[u] = bias[co0 + u]; acc1[u] = bias[co0 + u]; }

  const int cm = a > 0 ? a - 1 : 0;
  const bool mm = a > 0;
  const int cp = a < WH - 1 ? a + 1 : WH - 1;
  const bool mp = a < WH - 1;

  const int kh0 = (oh + 1) & 1;
#pragma unroll
  for (int dh = 0; dh < 2; dh++) {
    const int kh = kh0 + 2 * dh;
    const int ih = (oh + 1 - kh) >> 1;
    if (ih >= 0 && ih < Hin) {
      for (int ci = 0; ci < CIN; ci++) {
        const float* row = x + (((size_t)(n * CIN + ci)) * Hin + ih) * WH;
        float x0  = row[a];
        float xm1 = row[cm];  xm1 = mm ? xm1 : 0.f;
        float xp1 = row[cp];  xp1 = mp ? xp1 : 0.f;
        if (RELU_IN) {
          x0 = fmaxf(x0, 0.f); xm1 = fmaxf(xm1, 0.f); xp1 = fmaxf(xp1, 0.f);
        }
        const float* wp = w + ((size_t)(ci * Cout + co0)) * 16 + kh * 4;
#pragma unroll
        for (int u = 0; u < COT; u++) {
          const float* wr = wp + u * 16;
          acc0[u] = fmaf(x0,  wr[1], acc0[u]);
          acc0[u] = fmaf(xm1, wr[3], acc0[u]);
          acc1[u] = fmaf(xp1, wr[0], acc1[u]);
          acc1[u] = fmaf(x0,  wr[2], acc1[u]);
        }
      }
    }
  }
#pragma unroll
  for (int u = 0; u < COT; u++) {
    float v0 = acc0[u], v1 = acc1[u];
    if (RELU_OUT) { v0 = fmaxf(v0, 0.f); v1 = fmaxf(v1, 0.f); }
    float* row = y + (((size_t)(n * Cout + co0 + u)) * Hout + oh) * (2 * WH);
    ((float2*)row)[a] = make_float2(v0, v1);
  }
}

// ---------------- VQ: codebook -> fp64 (+ norms), once per call -----------
__global__ __launch_bounds__(256) void cvt_cb(
    const float* __restrict__ cb, double* __restrict__ cb64,
    double* __restrict__ cbn64) {
  const int k = blockIdx.x * 256 + threadIdx.x;   // 0..511
  double s = 0.0;
  for (int d = 0; d < 64; d++) {
    const double c = (double)cb[d * 512 + k];
    cb64[k * 64 + d] = c;
    s = fma(c, c, s);
  }
  cbn64[k] = s;
}

// ---------------- VQ v3: scalar fp64 codebook, in-place quantize ----------
// Block 256 = 64 positions x 4 code-groups (128 codes each, wave-uniform ->
// codebook via s_load). fp64 distances, exact first-min tie-break.
__global__ __launch_bounds__(256) void vq_kernel3(
    const float* __restrict__ cb, const double* __restrict__ cb64,
    const double* __restrict__ cbn64, float* __restrict__ zq) {
  __shared__ double redD[256];
  __shared__ int    redI[256];
  __shared__ int    bestIdx[64];
  const int tid = threadIdx.x;
  const int lane = tid & 63;
  const int g = rfl(tid >> 6);
  const int n = blockIdx.x >> 6, row = blockIdx.x & 63;
  float* zp = zq + ((size_t)n) * 262144 + (row << 6) + lane;

  double zr[64];
#pragma unroll
  for (int d = 0; d < 64; d++) zr[d] = (double)zp[(size_t)d * 4096];

  int best = 0;
  double bestd = 1e300;
  const double* cbk = cb64 + (size_t)g * 128 * 64;
  for (int j = 0; j < 128; j++) {
    const double* cw = cbk + j * 64;      // wave-uniform -> s_load
    double d0 = 0.0, d1 = 0.0, d2 = 0.0, d3 = 0.0;
#pragma unroll
    for (int d = 0; d < 64; d += 4) {
      d0 = fma(zr[d],     cw[d],     d0);
      d1 = fma(zr[d + 1], cw[d + 1], d1);
      d2 = fma(zr[d + 2], cw[d + 2], d2);
      d3 = fma(zr[d + 3], cw[d + 3], d3);
    }
    const int k = g * 128 + j;
    const double dist = cbn64[k] - 2.0 * ((d0 + d1) + (d2 + d3));
    if (dist < bestd) { bestd = dist; best = k; }
  }
  redD[tid] = bestd;
  redI[tid] = best;
  __syncthreads();
  if (tid < 64) {
    double bd = redD[lane];
    int bi = redI[lane];
#pragma unroll
    for (int gg = 1; gg < 4; gg++) {
      const double dd = redD[gg * 64 + lane];
      const int ii = redI[gg * 64 + lane];
      if (dd < bd || (dd == bd && ii < bi)) { bd = dd; bi = ii; }
    }
    bestIdx[lane] = bi;
  }
  __syncthreads();
  const int k = bestIdx[lane];
#pragma unroll
  for (int j = 0; j < 16; j++) {
    const int d = g * 16 + j;
    zp[(size_t)d * 4096] = cb[d * 512 + k];
  }
}

// -------------------------------------------------------------------------
extern "C" void kernel_launch(void* const* d_in, const int* in_sizes, int n_in,
                              void* d_out, int out_size, void* d_ws, size_t ws_size,
                              hipStream_t stream) {
  const float* x          = (const float*)d_in[0];
  const float* enc_w0     = (const float*)d_in[1];
  const float* enc_b0     = (const float*)d_in[2];
  const float* enc_w1     = (const float*)d_in[3];
  const float* enc_b1     = (const float*)d_in[4];
  const float* enc_wf     = (const float*)d_in[5];
  const float* enc_bf     = (const float*)d_in[6];
  const float* enc_res_w1 = (const float*)d_in[7];
  const float* enc_res_b1 = (const float*)d_in[8];
  const float* enc_res_w2 = (const float*)d_in[9];
  const float* enc_res_b2 = (const float*)d_in[10];
  const float* pre_w      = (const float*)d_in[11];
  const float* pre_b      = (const float*)d_in[12];
  const float* codebook   = (const float*)d_in[13];
  const float* dec_w      = (const float*)d_in[14];
  const float* dec_b      = (const float*)d_in[15];
  const float* dec_res_w1 = (const float*)d_in[16];
  const float* dec_res_b1 = (const float*)d_in[17];
  const float* dec_res_w2 = (const float*)d_in[18];
  const float* dec_res_b2 = (const float*)d_in[19];
  const float* up_w0      = (const float*)d_in[20];
  const float* up_b0      = (const float*)d_in[21];
  const float* up_w1      = (const float*)d_in[22];
  const float* up_b1      = (const float*)d_in[23];
  float* out = (float*)d_out;

  float* A = (float*)d_ws;         // 16,777,216 floats (64 MB)
  float* B = A + 16777216;         //  8,388,608 floats (32 MB)
  float* C = B + 8388608;          //  8,388,608 floats (32 MB)
  // fp64 codebook area inside A's free tail during the VQ window
  // (z occupies A[0 .. 4.19M); this sits at 24 MB offset, used only
  // between cvt_cb and vq_kernel3, long after conv1 consumed conv0's A).
  double* cb64  = (double*)(A + 6291456);   // 32768 doubles = 256 KB
  double* cbn64 = (double*)(A + 6291456 + 65536);  // 512 doubles

  const dim3 blk(256);
  const dim3 blk128(128);
  const int N = 16;

  // --- Encoder ---
  conv4s2_row<3, 16, true, 128><<<dim3(64, 4, N), blk, 0, stream>>>(
      x, enc_w0, enc_b0, A, 128, 64);
  conv4s2_64v3<64, 16, true><<<dim3(16, 8, N), blk, 0, stream>>>(
      A, enc_w1, enc_b1, B, 128);
  conv3_tile2<128, 16, false><<<dim3(16, 8, N), blk128, 0, stream>>>(
      B, enc_wf, enc_bf, C, 128);
  // enc res stack on C: 3x3 -> mid in A, fused 1x1-add in-place on C
  for (int i = 0; i < 2; i++) {
    conv3_tile2<128, 8, true><<<dim3(16, 4, N), blk128, 0, stream>>>(
        C, enc_res_w1 + (size_t)i * 32 * 128 * 9, enc_res_b1 + i * 32, A, 32);
    conv1x1_v4<32, 8, true, true><<<dim3(4, 16, N), blk, 0, stream>>>(
        A, enc_res_w2 + (size_t)i * 128 * 32, enc_res_b2 + i * 128, C, 4096, 128);
  }
  // pre: relu(C) -> z in A
  conv1x1_v4<128, 8, true, false><<<dim3(4, 8, N), blk, 0, stream>>>(
      C, pre_w, pre_b, A, 4096, 64);

  // --- VQ (in-place on A) ---
  cvt_cb<<<dim3(2), blk, 0, stream>>>(codebook, cb64, cbn64);
  vq_kernel3<<<dim3(1024), blk, 0, stream>>>(codebook, cb64, cbn64, A);

  // --- Decoder ---
  conv3_tile2<64, 16, false><<<dim3(16, 8, N), blk128, 0, stream>>>(
      A, dec_w, dec_b, B, 128);
  // dec res stack on B: 3x3 -> mid in A (free), fused 1x1-add in-place on B
  for (int i = 0; i < 2; i++) {
    conv3_tile2<128, 8, true><<<dim3(16, 4, N), blk128, 0, stream>>>(
        B, dec_res_w1 + (size_t)i * 32 * 128 * 9, dec_res_b1 + i * 32, A, 32);
    conv1x1_v4<32, 8, true, true><<<dim3(4, 16, N), blk, 0, stream>>>(
        A, dec_res_w2 + (size_t)i * 128 * 32, dec_res_b2 + i * 128, B, 4096, 128);
  }
  // up0: relu(B) -> A(16,64,128,128), ReLU
  convt_64v3<128, 16, true, true><<<dim3(32, 4, N), blk, 0, stream>>>(
      B, up_w0, up_b0, A, 64, 64);
  // up1: A -> out(16,3,256,256)
  convt_row<64, 3, false, false, 128><<<dim3(128, 1, N), blk, 0, stream>>>(
      A, up_w1, up_b1, out, 128, 3);
}